// Round 1
// baseline (3304.786 us; speedup 1.0000x reference)
//
#include <hip/hip_runtime.h>
#include <math.h>

#define BB 8
#define SS 1024
#define DD 768
#define HH 12
#define HDD 64
#define FFF 3072
#define NROW (BB*SS)

__device__ __forceinline__ float gelu_exact(float t) {
    return 0.5f * t * (1.0f + erff(t * 0.70710678118654752f));
}

// ---------------- LayerNorm: one block (256 thr) per row of 768 ----------------
__global__ __launch_bounds__(256) void ln_kernel(const float* __restrict__ x,
                                                 const float* __restrict__ w,
                                                 const float* __restrict__ b,
                                                 float* __restrict__ y) {
    int row = blockIdx.x;
    const float* xr = x + (size_t)row * DD;
    float* yr = y + (size_t)row * DD;
    int tid = threadIdx.x;
    float v0 = xr[tid], v1 = xr[tid + 256], v2 = xr[tid + 512];
    __shared__ float red[256], red2[256];
    red[tid]  = v0 + v1 + v2;
    red2[tid] = v0*v0 + v1*v1 + v2*v2;
    __syncthreads();
    for (int off = 128; off > 0; off >>= 1) {
        if (tid < off) { red[tid] += red[tid+off]; red2[tid] += red2[tid+off]; }
        __syncthreads();
    }
    float mu  = red[0] * (1.0f / DD);
    float var = red2[0] * (1.0f / DD) - mu * mu;
    float inv = rsqrtf(var + 1e-5f);
    yr[tid]       = (v0 - mu) * inv * w[tid]       + b[tid];
    yr[tid + 256] = (v1 - mu) * inv * w[tid + 256] + b[tid + 256];
    yr[tid + 512] = (v2 - mu) * inv * w[tid + 512] + b[tid + 512];
}

// ---------------- Tiled fp32 GEMM: C = act(A@B + bias) (+resid) ----------------
// 64x64 tile, BK=16, 256 threads, 4x4 micro-tile per thread.
// bmode 0: B row-major [K,N].  bmode 1: headed B[h][K][64], h = col0>>6.
__global__ __launch_bounds__(256) void gemm_kernel(
    const float* __restrict__ A, const float* __restrict__ Bm,
    const float* __restrict__ bias, const float* __restrict__ resid,
    float* __restrict__ C, int M, int N, int K, int bmode, int act)
{
    __shared__ float As[16][65];   // padded: conflict-free transpose-store
    __shared__ float Bs[16][64];
    int tid = threadIdx.x;
    int tx = tid & 15, ty = tid >> 4;
    int col0 = blockIdx.x * 64, row0 = blockIdx.y * 64;

    const float* Bt; int ldb, cb;
    if (bmode == 1) { Bt = Bm + (size_t)(col0 >> 6) * K * 64; ldb = 64; cb = 0; }
    else            { Bt = Bm; ldb = N; cb = col0; }

    int am  = tid >> 2;            // 0..63 : row within A tile
    int ak4 = (tid & 3) * 4;       // 0,4,8,12 : k within A tile
    int bk  = tid >> 4;            // 0..15 : k within B tile
    int bn4 = (tid & 15) * 4;      // col within B tile

    float acc[4][4] = {};
    for (int k0 = 0; k0 < K; k0 += 16) {
        float4 av = *(const float4*)(A + (size_t)(row0 + am) * K + k0 + ak4);
        As[ak4 + 0][am] = av.x; As[ak4 + 1][am] = av.y;
        As[ak4 + 2][am] = av.z; As[ak4 + 3][am] = av.w;
        float4 bv = *(const float4*)(Bt + (size_t)(k0 + bk) * ldb + cb + bn4);
        *(float4*)&Bs[bk][bn4] = bv;
        __syncthreads();
        #pragma unroll
        for (int kk = 0; kk < 16; kk++) {
            float a0 = As[kk][ty], a1 = As[kk][ty + 16],
                  a2 = As[kk][ty + 32], a3 = As[kk][ty + 48];
            float b0 = Bs[kk][tx], b1 = Bs[kk][tx + 16],
                  b2 = Bs[kk][tx + 32], b3 = Bs[kk][tx + 48];
            acc[0][0] = fmaf(a0, b0, acc[0][0]); acc[0][1] = fmaf(a0, b1, acc[0][1]);
            acc[0][2] = fmaf(a0, b2, acc[0][2]); acc[0][3] = fmaf(a0, b3, acc[0][3]);
            acc[1][0] = fmaf(a1, b0, acc[1][0]); acc[1][1] = fmaf(a1, b1, acc[1][1]);
            acc[1][2] = fmaf(a1, b2, acc[1][2]); acc[1][3] = fmaf(a1, b3, acc[1][3]);
            acc[2][0] = fmaf(a2, b0, acc[2][0]); acc[2][1] = fmaf(a2, b1, acc[2][1]);
            acc[2][2] = fmaf(a2, b2, acc[2][2]); acc[2][3] = fmaf(a2, b3, acc[2][3]);
            acc[3][0] = fmaf(a3, b0, acc[3][0]); acc[3][1] = fmaf(a3, b1, acc[3][1]);
            acc[3][2] = fmaf(a3, b2, acc[3][2]); acc[3][3] = fmaf(a3, b3, acc[3][3]);
        }
        __syncthreads();
    }
    #pragma unroll
    for (int i = 0; i < 4; i++) {
        int r = row0 + ty + i * 16;
        #pragma unroll
        for (int j = 0; j < 4; j++) {
            int c = col0 + tx + j * 16;
            float val = acc[i][j] + bias[c];
            if (act) val = gelu_exact(val);
            if (resid) val += resid[(size_t)r * N + c];
            C[(size_t)r * N + c] = val;
        }
    }
}

// ---------------- Fused attention: online softmax, 1 thread = 1 query row ------
// q,k,v layout: [b*S+s][h*64+e].  No 1/sqrt(HD) scale (matches reference).
__global__ __launch_bounds__(256) void attn_kernel(
    const float* __restrict__ q, const float* __restrict__ kg,
    const float* __restrict__ vg, float* __restrict__ ao)
{
    __shared__ float ks[64][64];
    __shared__ float vs[64][64];
    int tid = threadIdx.x;
    int b = blockIdx.z, h = blockIdx.y;
    int s = blockIdx.x * 256 + tid;

    const float* qr = q + (size_t)(b * SS + s) * DD + h * HDD;
    float qreg[64];
    #pragma unroll
    for (int e = 0; e < 64; e++) qreg[e] = qr[e];

    float m = -INFINITY, l = 0.0f;
    float acc[64];
    #pragma unroll
    for (int e = 0; e < 64; e++) acc[e] = 0.0f;

    for (int t0 = 0; t0 < SS; t0 += 64) {
        #pragma unroll
        for (int lidx = 0; lidx < 4; lidx++) {
            int lin = tid + lidx * 256;
            int jj = lin >> 4, e4 = (lin & 15) * 4;
            size_t gofs = (size_t)(b * SS + t0 + jj) * DD + h * HDD + e4;
            *(float4*)&ks[jj][e4] = *(const float4*)(kg + gofs);
            *(float4*)&vs[jj][e4] = *(const float4*)(vg + gofs);
        }
        __syncthreads();
        for (int j = 0; j < 64; j++) {
            const float4* kr = (const float4*)&ks[j][0];
            float sc = 0.0f;
            #pragma unroll
            for (int e4 = 0; e4 < 16; e4++) {
                float4 kv = kr[e4];
                sc = fmaf(qreg[e4*4+0], kv.x, sc);
                sc = fmaf(qreg[e4*4+1], kv.y, sc);
                sc = fmaf(qreg[e4*4+2], kv.z, sc);
                sc = fmaf(qreg[e4*4+3], kv.w, sc);
            }
            float mn   = fmaxf(m, sc);
            float corr = __expf(m - mn);
            float p    = __expf(sc - mn);
            l = l * corr + p;
            const float4* vr = (const float4*)&vs[j][0];
            #pragma unroll
            for (int e4 = 0; e4 < 16; e4++) {
                float4 vv = vr[e4];
                acc[e4*4+0] = fmaf(acc[e4*4+0], corr, p * vv.x);
                acc[e4*4+1] = fmaf(acc[e4*4+1], corr, p * vv.y);
                acc[e4*4+2] = fmaf(acc[e4*4+2], corr, p * vv.z);
                acc[e4*4+3] = fmaf(acc[e4*4+3], corr, p * vv.w);
            }
            m = mn;
        }
        __syncthreads();
    }
    float invl = 1.0f / l;
    float* outp = ao + (size_t)(b * SS + s) * DD + h * HDD;
    #pragma unroll
    for (int e = 0; e < 64; e++) outp[e] = acc[e] * invl;
}

// -------------------------------------------------------------------------------
extern "C" void kernel_launch(void* const* d_in, const int* in_sizes, int n_in,
                              void* d_out, int out_size, void* d_ws, size_t ws_size,
                              hipStream_t stream)
{
    (void)in_sizes; (void)n_in; (void)out_size; (void)ws_size;
    const float* x    = (const float*)d_in[0];
    const float* ln1w = (const float*)d_in[1];
    const float* ln1b = (const float*)d_in[2];
    const float* Wq   = (const float*)d_in[3];
    const float* bq   = (const float*)d_in[4];
    const float* Wk   = (const float*)d_in[5];
    const float* bk   = (const float*)d_in[6];
    const float* Wv   = (const float*)d_in[7];
    const float* bv   = (const float*)d_in[8];
    const float* Wp   = (const float*)d_in[9];
    const float* bp   = (const float*)d_in[10];
    const float* ln2w = (const float*)d_in[11];
    const float* ln2b = (const float*)d_in[12];
    const float* W1   = (const float*)d_in[13];
    const float* b1   = (const float*)d_in[14];
    const float* W2   = (const float*)d_in[15];
    const float* b2   = (const float*)d_in[16];
    float* out = (float*)d_out;

    float* ws  = (float*)d_ws;
    size_t nd  = (size_t)NROW * DD;
    float* y   = ws;            // LN output (reused for LN2)
    float* qb  = ws + nd;
    float* kb  = qb + nd;
    float* vb  = kb + nd;
    float* aob = vb + nd;
    float* hb  = ws + nd;       // FF intermediate reuses q..ao (4*nd = NROW*FFF)

    ln_kernel<<<NROW, 256, 0, stream>>>(x, ln1w, ln1b, y);

    dim3 g1(DD / 64, NROW / 64);
    gemm_kernel<<<g1, 256, 0, stream>>>(y, Wq, bq, nullptr, qb, NROW, DD, DD, 1, 0);
    gemm_kernel<<<g1, 256, 0, stream>>>(y, Wk, bk, nullptr, kb, NROW, DD, DD, 1, 0);
    gemm_kernel<<<g1, 256, 0, stream>>>(y, Wv, bv, nullptr, vb, NROW, DD, DD, 1, 0);

    dim3 ga(SS / 256, HH, BB);
    attn_kernel<<<ga, 256, 0, stream>>>(qb, kb, vb, aob);

    // projection + GELU + residual(x) -> out (= x1)
    gemm_kernel<<<g1, 256, 0, stream>>>(aob, Wp, bp, x, out, NROW, DD, DD, 0, 1);

    ln_kernel<<<NROW, 256, 0, stream>>>(out, ln2w, ln2b, y);

    dim3 g2(FFF / 64, NROW / 64);
    gemm_kernel<<<g2, 256, 0, stream>>>(y, W1, b1, nullptr, hb, NROW, FFF, DD, 0, 1);

    dim3 g3(DD / 64, NROW / 64);
    gemm_kernel<<<g3, 256, 0, stream>>>(hb, W2, b2, out, out, NROW, DD, FFF, 0, 1);
}

// Round 2
// 1606.424 us; speedup vs baseline: 2.0572x; 2.0572x over previous
//
#include <hip/hip_runtime.h>
#include <hip/hip_bf16.h>
#include <math.h>

#define BB 8
#define SS 1024
#define DD 768
#define HH 12
#define HDD 64
#define FFF 3072
#define NROW (BB*SS)
#define QKVN (3*DD)

typedef __hip_bfloat16 bf16;
typedef __bf16 bf16x8 __attribute__((ext_vector_type(8)));
typedef float floatx4 __attribute__((ext_vector_type(4)));

__device__ __forceinline__ float gelu_exact(float t) {
    return 0.5f * t * (1.0f + erff(t * 0.70710678118654752f));
}

__device__ __forceinline__ void gload16(const void* g, void* l) {
    __builtin_amdgcn_global_load_lds(
        (const __attribute__((address_space(1))) unsigned int*)g,
        (__attribute__((address_space(3))) unsigned int*)l, 16, 0, 0);
}

// ---------------- LayerNorm: fp32 in, bf16 out, one block per row ----------------
__global__ __launch_bounds__(256) void ln_kernel(const float* __restrict__ x,
                                                 const float* __restrict__ w,
                                                 const float* __restrict__ b,
                                                 bf16* __restrict__ y) {
    int row = blockIdx.x;
    const float* xr = x + (size_t)row * DD;
    bf16* yr = y + (size_t)row * DD;
    int tid = threadIdx.x;
    float v0 = xr[tid], v1 = xr[tid + 256], v2 = xr[tid + 512];
    __shared__ float red[256], red2[256];
    red[tid]  = v0 + v1 + v2;
    red2[tid] = v0*v0 + v1*v1 + v2*v2;
    __syncthreads();
    for (int off = 128; off > 0; off >>= 1) {
        if (tid < off) { red[tid] += red[tid+off]; red2[tid] += red2[tid+off]; }
        __syncthreads();
    }
    float mu  = red[0] * (1.0f / DD);
    float var = red2[0] * (1.0f / DD) - mu * mu;
    float inv = rsqrtf(var + 1e-5f);
    yr[tid]       = __float2bfloat16((v0 - mu) * inv * w[tid]       + b[tid]);
    yr[tid + 256] = __float2bfloat16((v1 - mu) * inv * w[tid + 256] + b[tid + 256]);
    yr[tid + 512] = __float2bfloat16((v2 - mu) * inv * w[tid + 512] + b[tid + 512]);
}

// ------------- transpose+cast: src fp32 [K,N] (or headed [H][K][64]) -> bf16 [N,K]
__global__ __launch_bounds__(256) void transpose_cast(
    const float* __restrict__ src, bf16* __restrict__ dst, int K, int N, int hmode)
{
    __shared__ float t[32][33];
    int k0 = blockIdx.x * 32, n0 = blockIdx.y * 32;
    int tx = threadIdx.x & 31, ty4 = threadIdx.x >> 5;
    #pragma unroll
    for (int i = 0; i < 4; i++) {
        int k = k0 + ty4 * 4 + i;
        int n = n0 + tx;
        size_t si = hmode ? ((size_t)(n >> 6) * K * 64 + (size_t)k * 64 + (n & 63))
                          : ((size_t)k * N + n);
        t[ty4 * 4 + i][tx] = src[si];
    }
    __syncthreads();
    #pragma unroll
    for (int i = 0; i < 4; i++) {
        int n = n0 + ty4 * 4 + i;
        int k = k0 + tx;
        dst[(size_t)n * K + k] = __float2bfloat16(t[tx][ty4 * 4 + i]);
    }
}

__global__ void concat_bias(const float* __restrict__ bq, const float* __restrict__ bk,
                            const float* __restrict__ bv, float* __restrict__ dst) {
    int i = blockIdx.x * 256 + threadIdx.x;
    if (i < DD) { dst[i] = bq[i]; dst[DD + i] = bk[i]; dst[2 * DD + i] = bv[i]; }
}

// ---------------- MFMA bf16 GEMM: C = epi(A @ Bt^T) --------------------------------
// A [M,K] bf16 row-major; Bt [N,K] bf16 row-major (i.e. B^T); 128x128 tile, BK=32.
// 256 threads = 4 waves, each wave a 64x64 quadrant (4x4 of 16x16x32 MFMA).
__global__ __launch_bounds__(256) void mfma_gemm(
    const bf16* __restrict__ A, const bf16* __restrict__ Bt,
    const float* __restrict__ bias, const float* __restrict__ resid,
    void* __restrict__ Cout, int M, int N, int K, int act, int out_bf16)
{
    __shared__ bf16 As[128 * 32];
    __shared__ bf16 Bs[128 * 32];
    int tid = threadIdx.x;
    int row0 = blockIdx.y * 128, col0 = blockIdx.x * 128;
    int wave = tid >> 6, lane = tid & 63;
    int wm = (wave >> 1) * 64, wn = (wave & 1) * 64;
    int l16 = lane & 15, quad = lane >> 4;

    int srow  = tid >> 2;        // 0..63
    int skoff = (tid & 3) * 8;   // k element offset of 16B chunk

    const bf16* gA0 = A  + (size_t)(row0 + srow)      * K + skoff;
    const bf16* gA1 = A  + (size_t)(row0 + 64 + srow) * K + skoff;
    const bf16* gB0 = Bt + (size_t)(col0 + srow)      * K + skoff;
    const bf16* gB1 = Bt + (size_t)(col0 + 64 + srow) * K + skoff;
    bf16* lA0 = As + tid * 8;
    bf16* lA1 = As + 2048 + tid * 8;
    bf16* lB0 = Bs + tid * 8;
    bf16* lB1 = Bs + 2048 + tid * 8;

    floatx4 acc[4][4] = {};

    for (int k0 = 0; k0 < K; k0 += 32) {
        gload16(gA0 + k0, lA0);
        gload16(gA1 + k0, lA1);
        gload16(gB0 + k0, lB0);
        gload16(gB1 + k0, lB1);
        __syncthreads();
        bf16x8 af[4], bfr[4];
        #pragma unroll
        for (int mt = 0; mt < 4; mt++)
            af[mt] = *(const bf16x8*)&As[(wm + mt * 16 + l16) * 32 + quad * 8];
        #pragma unroll
        for (int nt = 0; nt < 4; nt++)
            bfr[nt] = *(const bf16x8*)&Bs[(wn + nt * 16 + l16) * 32 + quad * 8];
        #pragma unroll
        for (int mt = 0; mt < 4; mt++)
            #pragma unroll
            for (int nt = 0; nt < 4; nt++)
                acc[mt][nt] = __builtin_amdgcn_mfma_f32_16x16x32_bf16(
                    af[mt], bfr[nt], acc[mt][nt], 0, 0, 0);
        __syncthreads();
    }

    #pragma unroll
    for (int mt = 0; mt < 4; mt++) {
        int rbase = row0 + wm + mt * 16 + quad * 4;
        #pragma unroll
        for (int nt = 0; nt < 4; nt++) {
            int col = col0 + wn + nt * 16 + l16;
            float bcol = bias[col];
            #pragma unroll
            for (int r = 0; r < 4; r++) {
                int row = rbase + r;
                float v = acc[mt][nt][r] + bcol;
                if (act) v = gelu_exact(v);
                if (resid) v += resid[(size_t)row * N + col];
                if (out_bf16) ((bf16*)Cout)[(size_t)row * N + col] = __float2bfloat16(v);
                else          ((float*)Cout)[(size_t)row * N + col] = v;
            }
        }
    }
}

// ---------------- Fused attention (fp32 math), qkv interleaved [row][2304] ---------
__global__ __launch_bounds__(256) void attn_kernel(
    const float* __restrict__ qkv, bf16* __restrict__ ao)
{
    __shared__ float ks[64][64];
    __shared__ float vs[64][64];
    int tid = threadIdx.x;
    int b = blockIdx.z, h = blockIdx.y;
    int s = blockIdx.x * 256 + tid;

    const float* qr = qkv + (size_t)(b * SS + s) * QKVN + h * HDD;
    float qreg[64];
    #pragma unroll
    for (int e = 0; e < 64; e++) qreg[e] = qr[e];

    float m = -INFINITY, l = 0.0f;
    float acc[64];
    #pragma unroll
    for (int e = 0; e < 64; e++) acc[e] = 0.0f;

    for (int t0 = 0; t0 < SS; t0 += 64) {
        #pragma unroll
        for (int lidx = 0; lidx < 4; lidx++) {
            int lin = tid + lidx * 256;
            int jj = lin >> 4, e4 = (lin & 15) * 4;
            size_t gofs = (size_t)(b * SS + t0 + jj) * QKVN + h * HDD + e4;
            *(float4*)&ks[jj][e4] = *(const float4*)(qkv + DD + gofs);
            *(float4*)&vs[jj][e4] = *(const float4*)(qkv + 2 * DD + gofs);
        }
        __syncthreads();
        for (int j = 0; j < 64; j++) {
            const float4* kr = (const float4*)&ks[j][0];
            float sc = 0.0f;
            #pragma unroll
            for (int e4 = 0; e4 < 16; e4++) {
                float4 kv = kr[e4];
                sc = fmaf(qreg[e4*4+0], kv.x, sc);
                sc = fmaf(qreg[e4*4+1], kv.y, sc);
                sc = fmaf(qreg[e4*4+2], kv.z, sc);
                sc = fmaf(qreg[e4*4+3], kv.w, sc);
            }
            float mn   = fmaxf(m, sc);
            float corr = __expf(m - mn);
            float p    = __expf(sc - mn);
            l = l * corr + p;
            const float4* vr = (const float4*)&vs[j][0];
            #pragma unroll
            for (int e4 = 0; e4 < 16; e4++) {
                float4 vv = vr[e4];
                acc[e4*4+0] = fmaf(acc[e4*4+0], corr, p * vv.x);
                acc[e4*4+1] = fmaf(acc[e4*4+1], corr, p * vv.y);
                acc[e4*4+2] = fmaf(acc[e4*4+2], corr, p * vv.z);
                acc[e4*4+3] = fmaf(acc[e4*4+3], corr, p * vv.w);
            }
            m = mn;
        }
        __syncthreads();
    }
    float invl = 1.0f / l;
    bf16* outp = ao + (size_t)(b * SS + s) * DD + h * HDD;
    #pragma unroll
    for (int e = 0; e < 64; e++) outp[e] = __float2bfloat16(acc[e] * invl);
}

// -----------------------------------------------------------------------------------
extern "C" void kernel_launch(void* const* d_in, const int* in_sizes, int n_in,
                              void* d_out, int out_size, void* d_ws, size_t ws_size,
                              hipStream_t stream)
{
    (void)in_sizes; (void)n_in; (void)out_size; (void)ws_size;
    const float* x    = (const float*)d_in[0];
    const float* ln1w = (const float*)d_in[1];
    const float* ln1b = (const float*)d_in[2];
    const float* Wq   = (const float*)d_in[3];
    const float* bq   = (const float*)d_in[4];
    const float* Wk   = (const float*)d_in[5];
    const float* bk   = (const float*)d_in[6];
    const float* Wv   = (const float*)d_in[7];
    const float* bv   = (const float*)d_in[8];
    const float* Wp   = (const float*)d_in[9];
    const float* bp   = (const float*)d_in[10];
    const float* ln2w = (const float*)d_in[11];
    const float* ln2b = (const float*)d_in[12];
    const float* W1   = (const float*)d_in[13];
    const float* b1   = (const float*)d_in[14];
    const float* W2   = (const float*)d_in[15];
    const float* b2   = (const float*)d_in[16];
    float* out = (float*)d_out;

    char* p = (char*)d_ws;
    auto alloc = [&](size_t bytes) { char* r = p; p += (bytes + 255) & ~255ull; return r; };
    bf16*  Wqkvt = (bf16*)alloc((size_t)QKVN * DD * 2);   // [2304][768]
    bf16*  Wpt   = (bf16*)alloc((size_t)DD * DD * 2);     // [768][768]
    bf16*  W1t   = (bf16*)alloc((size_t)FFF * DD * 2);    // [3072][768]
    bf16*  W2t   = (bf16*)alloc((size_t)DD * FFF * 2);    // [768][3072]
    float* bqkv  = (float*)alloc((size_t)QKVN * 4);
    bf16*  yb    = (bf16*)alloc((size_t)NROW * DD * 2);
    bf16*  aob   = (bf16*)alloc((size_t)NROW * DD * 2);
    float* qkv   = (float*)alloc((size_t)NROW * QKVN * 4);
    bf16*  hb    = (bf16*)qkv;   // FF intermediate reuses qkv space (50MB <= 75.5MB)

    // weight prep (~42 MB traffic, ~7 us)
    transpose_cast<<<dim3(DD/32, DD/32),  256, 0, stream>>>(Wq, Wqkvt,            DD, DD, 1);
    transpose_cast<<<dim3(DD/32, DD/32),  256, 0, stream>>>(Wk, Wqkvt + DD*DD,    DD, DD, 1);
    transpose_cast<<<dim3(DD/32, DD/32),  256, 0, stream>>>(Wv, Wqkvt + 2*DD*DD,  DD, DD, 1);
    transpose_cast<<<dim3(DD/32, DD/32),  256, 0, stream>>>(Wp, Wpt,              DD, DD, 0);
    transpose_cast<<<dim3(DD/32, FFF/32), 256, 0, stream>>>(W1, W1t,              DD, FFF, 0);
    transpose_cast<<<dim3(FFF/32, DD/32), 256, 0, stream>>>(W2, W2t,              FFF, DD, 0);
    concat_bias<<<3, 256, 0, stream>>>(bq, bk, bv, bqkv);

    ln_kernel<<<NROW, 256, 0, stream>>>(x, ln1w, ln1b, yb);

    // fused QKV: [8192,768] @ [768,2304] -> qkv fp32 [8192,2304]
    mfma_gemm<<<dim3(QKVN/128, NROW/128), 256, 0, stream>>>(
        yb, Wqkvt, bqkv, nullptr, qkv, NROW, QKVN, DD, 0, 0);

    attn_kernel<<<dim3(SS/256, HH, BB), 256, 0, stream>>>(qkv, aob);

    // projection + GELU + residual(x) -> out fp32
    mfma_gemm<<<dim3(DD/128, NROW/128), 256, 0, stream>>>(
        aob, Wpt, bp, x, out, NROW, DD, DD, 1, 0);

    ln_kernel<<<NROW, 256, 0, stream>>>(out, ln2w, ln2b, yb);

    // FF1 + GELU -> hb bf16
    mfma_gemm<<<dim3(FFF/128, NROW/128), 256, 0, stream>>>(
        yb, W1t, b1, nullptr, hb, NROW, FFF, DD, 1, 1);

    // FF2 + GELU + residual(out) -> out fp32
    mfma_gemm<<<dim3(DD/128, NROW/128), 256, 0, stream>>>(
        hb, W2t, b2, out, out, NROW, DD, FFF, 1, 0);
}

// Round 3
// 518.992 us; speedup vs baseline: 6.3677x; 3.0953x over previous
//
#include <hip/hip_runtime.h>
#include <hip/hip_bf16.h>
#include <math.h>

#define BB 8
#define SS 1024
#define DD 768
#define HH 12
#define HDD 64
#define FFF 3072
#define NROW (BB*SS)
#define QKVN (3*DD)

typedef __hip_bfloat16 bf16;
typedef __bf16 bf16x8 __attribute__((ext_vector_type(8)));
typedef float floatx4 __attribute__((ext_vector_type(4)));

__device__ __forceinline__ float gelu_exact(float t) {
    return 0.5f * t * (1.0f + erff(t * 0.70710678118654752f));
}

__device__ __forceinline__ unsigned short f2bfbits(float f) {
    bf16 h = __float2bfloat16(f);
    return __builtin_bit_cast(unsigned short, h);
}

__device__ __forceinline__ void gload16(const void* g, void* l) {
    __builtin_amdgcn_global_load_lds(
        (const __attribute__((address_space(1))) unsigned int*)g,
        (__attribute__((address_space(3))) unsigned int*)l, 16, 0, 0);
}

// ---------------- LayerNorm: fp32 in, bf16 out, one block per row ----------------
__global__ __launch_bounds__(256) void ln_kernel(const float* __restrict__ x,
                                                 const float* __restrict__ w,
                                                 const float* __restrict__ b,
                                                 bf16* __restrict__ y) {
    int row = blockIdx.x;
    const float* xr = x + (size_t)row * DD;
    bf16* yr = y + (size_t)row * DD;
    int tid = threadIdx.x;
    float v0 = xr[tid], v1 = xr[tid + 256], v2 = xr[tid + 512];
    __shared__ float red[256], red2[256];
    red[tid]  = v0 + v1 + v2;
    red2[tid] = v0*v0 + v1*v1 + v2*v2;
    __syncthreads();
    for (int off = 128; off > 0; off >>= 1) {
        if (tid < off) { red[tid] += red[tid+off]; red2[tid] += red2[tid+off]; }
        __syncthreads();
    }
    float mu  = red[0] * (1.0f / DD);
    float var = red2[0] * (1.0f / DD) - mu * mu;
    float inv = rsqrtf(var + 1e-5f);
    yr[tid]       = __float2bfloat16((v0 - mu) * inv * w[tid]       + b[tid]);
    yr[tid + 256] = __float2bfloat16((v1 - mu) * inv * w[tid + 256] + b[tid + 256]);
    yr[tid + 512] = __float2bfloat16((v2 - mu) * inv * w[tid + 512] + b[tid + 512]);
}

// ------------- transpose+cast: src fp32 [K,N] (or headed [H][K][64]) -> bf16 [N,K]
__global__ __launch_bounds__(256) void transpose_cast(
    const float* __restrict__ src, bf16* __restrict__ dst, int K, int N, int hmode)
{
    __shared__ float t[32][33];
    int k0 = blockIdx.x * 32, n0 = blockIdx.y * 32;
    int tx = threadIdx.x & 31, ty4 = threadIdx.x >> 5;
    #pragma unroll
    for (int i = 0; i < 4; i++) {
        int k = k0 + ty4 * 4 + i;
        int n = n0 + tx;
        size_t si = hmode ? ((size_t)(n >> 6) * K * 64 + (size_t)k * 64 + (n & 63))
                          : ((size_t)k * N + n);
        t[ty4 * 4 + i][tx] = src[si];
    }
    __syncthreads();
    #pragma unroll
    for (int i = 0; i < 4; i++) {
        int n = n0 + ty4 * 4 + i;
        int k = k0 + tx;
        dst[(size_t)n * K + k] = __float2bfloat16(t[tx][ty4 * 4 + i]);
    }
}

__global__ void concat_bias(const float* __restrict__ bq, const float* __restrict__ bk,
                            const float* __restrict__ bv, float* __restrict__ dst) {
    int i = blockIdx.x * 256 + threadIdx.x;
    if (i < DD) { dst[i] = bq[i]; dst[DD + i] = bk[i]; dst[2 * DD + i] = bv[i]; }
}

// ---------------- MFMA bf16 GEMM: C = epi(A @ Bt^T) --------------------------------
// A [M,K] bf16 row-major; Bt [N,K] bf16 row-major; 128x128 tile, BK=32.
// qkvmode: N=2304, scatter epilogue into qh [bh,s,64], kh swizzled, vT swizzled.
__global__ __launch_bounds__(256) void mfma_gemm(
    const bf16* __restrict__ A, const bf16* __restrict__ Bt,
    const float* __restrict__ bias, const float* __restrict__ resid,
    void* __restrict__ Cout, int M, int N, int K, int act, int out_bf16,
    int qkvmode, bf16* __restrict__ qhg, bf16* __restrict__ khg, bf16* __restrict__ vtg)
{
    __shared__ bf16 As[128 * 32];
    __shared__ bf16 Bs[128 * 32];
    int tid = threadIdx.x;
    int row0 = blockIdx.y * 128, col0 = blockIdx.x * 128;
    int wave = tid >> 6, lane = tid & 63;
    int wm = (wave >> 1) * 64, wn = (wave & 1) * 64;
    int l16 = lane & 15, quad = lane >> 4;

    int srow  = tid >> 2;
    int skoff = (tid & 3) * 8;

    const bf16* gA0 = A  + (size_t)(row0 + srow)      * K + skoff;
    const bf16* gA1 = A  + (size_t)(row0 + 64 + srow) * K + skoff;
    const bf16* gB0 = Bt + (size_t)(col0 + srow)      * K + skoff;
    const bf16* gB1 = Bt + (size_t)(col0 + 64 + srow) * K + skoff;
    bf16* lA0 = As + tid * 8;
    bf16* lA1 = As + 2048 + tid * 8;
    bf16* lB0 = Bs + tid * 8;
    bf16* lB1 = Bs + 2048 + tid * 8;

    floatx4 acc[4][4] = {};

    for (int k0 = 0; k0 < K; k0 += 32) {
        gload16(gA0 + k0, lA0);
        gload16(gA1 + k0, lA1);
        gload16(gB0 + k0, lB0);
        gload16(gB1 + k0, lB1);
        __syncthreads();
        bf16x8 af[4], bfr[4];
        #pragma unroll
        for (int mt = 0; mt < 4; mt++)
            af[mt] = *(const bf16x8*)&As[(wm + mt * 16 + l16) * 32 + quad * 8];
        #pragma unroll
        for (int nt = 0; nt < 4; nt++)
            bfr[nt] = *(const bf16x8*)&Bs[(wn + nt * 16 + l16) * 32 + quad * 8];
        #pragma unroll
        for (int mt = 0; mt < 4; mt++)
            #pragma unroll
            for (int nt = 0; nt < 4; nt++)
                acc[mt][nt] = __builtin_amdgcn_mfma_f32_16x16x32_bf16(
                    af[mt], bfr[nt], acc[mt][nt], 0, 0, 0);
        __syncthreads();
    }

    if (qkvmode) {
        #pragma unroll
        for (int mt = 0; mt < 4; mt++) {
            int rbase = row0 + wm + mt * 16 + quad * 4;
            int bq_ = rbase >> 10, sb = rbase & 1023;
            #pragma unroll
            for (int nt = 0; nt < 4; nt++) {
                int col = col0 + wn + nt * 16 + l16;
                float bcol = bias[col];
                if (col < DD) {
                    int hh = col >> 6, e = col & 63;
                    bf16* base = qhg + (((size_t)bq_ * HH + hh) * SS + sb) * 64 + e;
                    #pragma unroll
                    for (int r = 0; r < 4; r++)
                        base[(size_t)r * 64] = __float2bfloat16(acc[mt][nt][r] + bcol);
                } else if (col < 2 * DD) {
                    int cc = col - DD, hh = cc >> 6, e = cc & 63;
                    bf16* base = khg + (((size_t)bq_ * HH + hh) * SS) * 64;
                    #pragma unroll
                    for (int r = 0; r < 4; r++) {
                        int s = sb + r;
                        int pos = (((e >> 3) ^ (s & 7)) << 3) | (e & 7);
                        base[(size_t)s * 64 + pos] = __float2bfloat16(acc[mt][nt][r] + bcol);
                    }
                } else {
                    int cc = col - 2 * DD, hh = cc >> 6, e = cc & 63;
                    int c_t = sb >> 3;
                    int sc = (c_t & ~7) | ((c_t & 7) ^ (e & 7));
                    size_t off = (((size_t)bq_ * HH + hh) * 64 + e) * SS + sc * 8 + (sb & 7);
                    ushort4 pk;
                    pk.x = f2bfbits(acc[mt][nt][0] + bcol);
                    pk.y = f2bfbits(acc[mt][nt][1] + bcol);
                    pk.z = f2bfbits(acc[mt][nt][2] + bcol);
                    pk.w = f2bfbits(acc[mt][nt][3] + bcol);
                    *(ushort4*)&vtg[off] = pk;
                }
            }
        }
        return;
    }

    #pragma unroll
    for (int mt = 0; mt < 4; mt++) {
        int rbase = row0 + wm + mt * 16 + quad * 4;
        #pragma unroll
        for (int nt = 0; nt < 4; nt++) {
            int col = col0 + wn + nt * 16 + l16;
            float bcol = bias[col];
            #pragma unroll
            for (int r = 0; r < 4; r++) {
                int row = rbase + r;
                float v = acc[mt][nt][r] + bcol;
                if (act) v = gelu_exact(v);
                if (resid) v += resid[(size_t)row * N + col];
                if (out_bf16) ((bf16*)Cout)[(size_t)row * N + col] = __float2bfloat16(v);
                else          ((float*)Cout)[(size_t)row * N + col] = v;
            }
        }
    }
}

// ---------------- MFMA flash attention ---------------------------------------------
// Block: 128 q-rows of one (b,h); 4 waves x 32 rows. K/V staged 64-token tiles.
// qh [bh][s][64] plain; kh [bh][s][64] chunk-swizzled; vT [bh][e][1024] chunk-swizzled.
__global__ __launch_bounds__(256) void attn_mfma(
    const bf16* __restrict__ qh, const bf16* __restrict__ kh,
    const bf16* __restrict__ vT, bf16* __restrict__ ao)
{
    __shared__ bf16 Ks[64 * 64];
    __shared__ bf16 Vs[64 * 64];
    __shared__ bf16 Ps[128 * 64];

    int tid = threadIdx.x;
    int wave = tid >> 6, lane = tid & 63;
    int l16 = lane & 15, quad = lane >> 4;
    int b = blockIdx.z, h = blockIdx.y;
    int bh = b * HH + h;
    int s0 = blockIdx.x * 128;
    int wm = wave * 32;

    const bf16* qbase = qh + ((size_t)bh * SS) * HDD;
    const bf16* kbase = kh + ((size_t)bh * SS) * HDD;
    const bf16* vbase = vT + ((size_t)bh * HDD) * SS;

    // Q fragments, held in registers for the whole K-loop
    bf16x8 qf[2][2];
    #pragma unroll
    for (int mt = 0; mt < 2; mt++)
        #pragma unroll
        for (int ks = 0; ks < 2; ks++)
            qf[mt][ks] = *(const bf16x8*)(qbase +
                (size_t)(s0 + wm + mt * 16 + l16) * HDD + ks * 32 + quad * 8);

    floatx4 oacc[2][4] = {};
    float mrow[2][4], lrow[2][4];
    #pragma unroll
    for (int mt = 0; mt < 2; mt++)
        #pragma unroll
        for (int r = 0; r < 4; r++) { mrow[mt][r] = -INFINITY; lrow[mt][r] = 0.0f; }

    for (int t0 = 0; t0 < SS; t0 += 64) {
        __syncthreads();   // all waves done reading previous Ks/Vs
        #pragma unroll
        for (int i = 0; i < 2; i++) {
            int c = tid + i * 256;
            gload16(kbase + (size_t)t0 * 64 + c * 8, Ks + c * 8);
            gload16(vbase + (size_t)(c >> 3) * SS + t0 + (c & 7) * 8, Vs + c * 8);
        }
        __syncthreads();   // staging complete (vmcnt drained by barrier)

        // ---- S = Q K^T (32x64 per wave) ----
        floatx4 sacc[2][4] = {};
        #pragma unroll
        for (int nt = 0; nt < 4; nt++) {
            int t = nt * 16 + l16;
            #pragma unroll
            for (int ks = 0; ks < 2; ks++) {
                int pos = (quad + 4 * ks) ^ (t & 7);
                bf16x8 bfr = *(const bf16x8*)(Ks + t * 64 + pos * 8);
                #pragma unroll
                for (int mt = 0; mt < 2; mt++)
                    sacc[mt][nt] = __builtin_amdgcn_mfma_f32_16x16x32_bf16(
                        qf[mt][ks], bfr, sacc[mt][nt], 0, 0, 0);
            }
        }

        // ---- online softmax + P->LDS ----
        #pragma unroll
        for (int mt = 0; mt < 2; mt++) {
            #pragma unroll
            for (int r = 0; r < 4; r++) {
                float sv0 = sacc[mt][0][r], sv1 = sacc[mt][1][r];
                float sv2 = sacc[mt][2][r], sv3 = sacc[mt][3][r];
                float mx = fmaxf(fmaxf(sv0, sv1), fmaxf(sv2, sv3));
                #pragma unroll
                for (int d = 1; d < 16; d <<= 1) mx = fmaxf(mx, __shfl_xor(mx, d, 64));
                float mnew = fmaxf(mrow[mt][r], mx);
                float corr = __expf(mrow[mt][r] - mnew);
                float p0 = __expf(sv0 - mnew), p1 = __expf(sv1 - mnew);
                float p2 = __expf(sv2 - mnew), p3 = __expf(sv3 - mnew);
                float psum = p0 + p1 + p2 + p3;
                #pragma unroll
                for (int d = 1; d < 16; d <<= 1) psum += __shfl_xor(psum, d, 64);
                lrow[mt][r] = lrow[mt][r] * corr + psum;
                mrow[mt][r] = mnew;
                #pragma unroll
                for (int nte = 0; nte < 4; nte++) oacc[mt][nte][r] *= corr;
                int row = wm + mt * 16 + quad * 4 + r;
                int r7 = row & 7;
                float pv[4] = {p0, p1, p2, p3};
                #pragma unroll
                for (int nt = 0; nt < 4; nt++) {
                    int col = nt * 16 + l16;
                    int pos = (((col >> 3) ^ r7) << 3) | (col & 7);
                    Ps[row * 64 + pos] = __float2bfloat16(pv[nt]);
                }
            }
        }

        // ---- O += P V (32x64 per wave; Ps region private to wave) ----
        #pragma unroll
        for (int mt = 0; mt < 2; mt++) {
            int prow = wm + mt * 16 + l16;
            #pragma unroll
            for (int ks = 0; ks < 2; ks++) {
                int pos = (quad + 4 * ks) ^ (prow & 7);
                bf16x8 pf = *(const bf16x8*)(Ps + prow * 64 + pos * 8);
                #pragma unroll
                for (int nte = 0; nte < 4; nte++) {
                    int e = nte * 16 + l16;
                    int vpos = (quad + 4 * ks) ^ (e & 7);
                    bf16x8 vf = *(const bf16x8*)(Vs + e * 64 + vpos * 8);
                    oacc[mt][nte] = __builtin_amdgcn_mfma_f32_16x16x32_bf16(
                        pf, vf, oacc[mt][nte], 0, 0, 0);
                }
            }
        }
    }

    // ---- epilogue: O /= l, write bf16 [row][768] ----
    #pragma unroll
    for (int mt = 0; mt < 2; mt++) {
        #pragma unroll
        for (int r = 0; r < 4; r++) {
            int srow = s0 + wm + mt * 16 + quad * 4 + r;
            float invl = 1.0f / lrow[mt][r];
            bf16* op = ao + ((size_t)b * SS + srow) * DD + h * HDD;
            #pragma unroll
            for (int nte = 0; nte < 4; nte++)
                op[nte * 16 + l16] = __float2bfloat16(oacc[mt][nte][r] * invl);
        }
    }
}

// -----------------------------------------------------------------------------------
extern "C" void kernel_launch(void* const* d_in, const int* in_sizes, int n_in,
                              void* d_out, int out_size, void* d_ws, size_t ws_size,
                              hipStream_t stream)
{
    (void)in_sizes; (void)n_in; (void)out_size; (void)ws_size;
    const float* x    = (const float*)d_in[0];
    const float* ln1w = (const float*)d_in[1];
    const float* ln1b = (const float*)d_in[2];
    const float* Wq   = (const float*)d_in[3];
    const float* bq   = (const float*)d_in[4];
    const float* Wk   = (const float*)d_in[5];
    const float* bk   = (const float*)d_in[6];
    const float* Wv   = (const float*)d_in[7];
    const float* bv   = (const float*)d_in[8];
    const float* Wp   = (const float*)d_in[9];
    const float* bp   = (const float*)d_in[10];
    const float* ln2w = (const float*)d_in[11];
    const float* ln2b = (const float*)d_in[12];
    const float* W1   = (const float*)d_in[13];
    const float* b1   = (const float*)d_in[14];
    const float* W2   = (const float*)d_in[15];
    const float* b2   = (const float*)d_in[16];
    float* out = (float*)d_out;

    char* p = (char*)d_ws;
    auto alloc = [&](size_t bytes) { char* r = p; p += (bytes + 255) & ~255ull; return r; };
    bf16*  Wqkvt = (bf16*)alloc((size_t)QKVN * DD * 2);
    bf16*  Wpt   = (bf16*)alloc((size_t)DD * DD * 2);
    bf16*  W1t   = (bf16*)alloc((size_t)FFF * DD * 2);
    bf16*  W2t   = (bf16*)alloc((size_t)DD * FFF * 2);
    float* bqkv  = (float*)alloc((size_t)QKVN * 4);
    bf16*  yb    = (bf16*)alloc((size_t)NROW * DD * 2);
    char*  dynr  = alloc((size_t)NROW * DD * 2 + 3 * ((size_t)NROW * DD * 2));
    bf16*  aob   = (bf16*)dynr;                                // [row][768]
    bf16*  qhb   = (bf16*)(dynr + (size_t)NROW * DD * 2);      // [bh][s][64]
    bf16*  khb   = qhb + (size_t)NROW * DD;                    // swizzled
    bf16*  vtb   = khb + (size_t)NROW * DD;                    // [bh][e][1024] swizzled
    bf16*  hb    = (bf16*)dynr;   // FF intermediate (50MB) reuses aob+qkv region (50.3MB)

    transpose_cast<<<dim3(DD/32, DD/32),  256, 0, stream>>>(Wq, Wqkvt,            DD, DD, 1);
    transpose_cast<<<dim3(DD/32, DD/32),  256, 0, stream>>>(Wk, Wqkvt + DD*DD,    DD, DD, 1);
    transpose_cast<<<dim3(DD/32, DD/32),  256, 0, stream>>>(Wv, Wqkvt + 2*DD*DD,  DD, DD, 1);
    transpose_cast<<<dim3(DD/32, DD/32),  256, 0, stream>>>(Wp, Wpt,              DD, DD, 0);
    transpose_cast<<<dim3(DD/32, FFF/32), 256, 0, stream>>>(W1, W1t,              DD, FFF, 0);
    transpose_cast<<<dim3(FFF/32, DD/32), 256, 0, stream>>>(W2, W2t,              FFF, DD, 0);
    concat_bias<<<3, 256, 0, stream>>>(bq, bk, bv, bqkv);

    ln_kernel<<<NROW, 256, 0, stream>>>(x, ln1w, ln1b, yb);

    // fused QKV GEMM with head-separating scatter epilogue
    mfma_gemm<<<dim3(QKVN/128, NROW/128), 256, 0, stream>>>(
        yb, Wqkvt, bqkv, nullptr, nullptr, NROW, QKVN, DD, 0, 0, 1, qhb, khb, vtb);

    attn_mfma<<<dim3(SS/128, HH, BB), 256, 0, stream>>>(qhb, khb, vtb, aob);

    // projection + GELU + residual(x) -> out fp32
    mfma_gemm<<<dim3(DD/128, NROW/128), 256, 0, stream>>>(
        aob, Wpt, bp, x, out, NROW, DD, DD, 1, 0, 0, nullptr, nullptr, nullptr);

    ln_kernel<<<NROW, 256, 0, stream>>>(out, ln2w, ln2b, yb);

    // FF1 + GELU -> hb bf16
    mfma_gemm<<<dim3(FFF/128, NROW/128), 256, 0, stream>>>(
        yb, W1t, b1, nullptr, hb, NROW, FFF, DD, 1, 1, 0, nullptr, nullptr, nullptr);

    // FF2 + GELU + residual(out) -> out fp32
    mfma_gemm<<<dim3(DD/128, NROW/128), 256, 0, stream>>>(
        hb, W2t, b2, out, out, NROW, DD, FFF, 1, 0, 0, nullptr, nullptr, nullptr);
}

// Round 4
// 495.205 us; speedup vs baseline: 6.6736x; 1.0480x over previous
//
#include <hip/hip_runtime.h>
#include <hip/hip_bf16.h>
#include <math.h>

#define BB 8
#define SS 1024
#define DD 768
#define HH 12
#define HDD 64
#define FFF 3072
#define NROW (BB*SS)
#define QKVN (3*DD)

typedef __hip_bfloat16 bf16;
typedef __bf16 bf16x8 __attribute__((ext_vector_type(8)));
typedef float floatx4 __attribute__((ext_vector_type(4)));

__device__ __forceinline__ float gelu_exact(float t) {
    return 0.5f * t * (1.0f + erff(t * 0.70710678118654752f));
}

__device__ __forceinline__ unsigned short f2bfbits(float f) {
    bf16 h = __float2bfloat16(f);
    return __builtin_bit_cast(unsigned short, h);
}

__device__ __forceinline__ void gload16(const void* g, void* l) {
    __builtin_amdgcn_global_load_lds(
        (const __attribute__((address_space(1))) unsigned int*)g,
        (__attribute__((address_space(3))) unsigned int*)l, 16, 0, 0);
}

// ---------------- LayerNorm: fp32 in, bf16 out, one block per row ----------------
__global__ __launch_bounds__(256) void ln_kernel(const float* __restrict__ x,
                                                 const float* __restrict__ w,
                                                 const float* __restrict__ b,
                                                 bf16* __restrict__ y) {
    int row = blockIdx.x;
    const float* xr = x + (size_t)row * DD;
    bf16* yr = y + (size_t)row * DD;
    int tid = threadIdx.x;
    float v0 = xr[tid], v1 = xr[tid + 256], v2 = xr[tid + 512];
    __shared__ float red[256], red2[256];
    red[tid]  = v0 + v1 + v2;
    red2[tid] = v0*v0 + v1*v1 + v2*v2;
    __syncthreads();
    for (int off = 128; off > 0; off >>= 1) {
        if (tid < off) { red[tid] += red[tid+off]; red2[tid] += red2[tid+off]; }
        __syncthreads();
    }
    float mu  = red[0] * (1.0f / DD);
    float var = red2[0] * (1.0f / DD) - mu * mu;
    float inv = rsqrtf(var + 1e-5f);
    yr[tid]       = __float2bfloat16((v0 - mu) * inv * w[tid]       + b[tid]);
    yr[tid + 256] = __float2bfloat16((v1 - mu) * inv * w[tid + 256] + b[tid + 256]);
    yr[tid + 512] = __float2bfloat16((v2 - mu) * inv * w[tid + 512] + b[tid + 512]);
}

// ------------- transpose+cast: src fp32 [K,N] (or headed [H][K][64]) -> bf16 [N,K]
__global__ __launch_bounds__(256) void transpose_cast(
    const float* __restrict__ src, bf16* __restrict__ dst, int K, int N, int hmode)
{
    __shared__ float t[32][33];
    int k0 = blockIdx.x * 32, n0 = blockIdx.y * 32;
    int tx = threadIdx.x & 31, ty4 = threadIdx.x >> 5;
    #pragma unroll
    for (int i = 0; i < 4; i++) {
        int k = k0 + ty4 * 4 + i;
        int n = n0 + tx;
        size_t si = hmode ? ((size_t)(n >> 6) * K * 64 + (size_t)k * 64 + (n & 63))
                          : ((size_t)k * N + n);
        t[ty4 * 4 + i][tx] = src[si];
    }
    __syncthreads();
    #pragma unroll
    for (int i = 0; i < 4; i++) {
        int n = n0 + ty4 * 4 + i;
        int k = k0 + tx;
        dst[(size_t)n * K + k] = __float2bfloat16(t[tx][ty4 * 4 + i]);
    }
}

__global__ void concat_bias(const float* __restrict__ bq, const float* __restrict__ bk,
                            const float* __restrict__ bv, float* __restrict__ dst) {
    int i = blockIdx.x * 256 + threadIdx.x;
    if (i < DD) { dst[i] = bq[i]; dst[DD + i] = bk[i]; dst[2 * DD + i] = bv[i]; }
}

// ---------------- MFMA bf16 GEMM, double-buffered: C = epi(A @ Bt^T) ---------------
// MT = rows per block (128 or 64); N-tile fixed 128. One barrier per K-iter;
// tile k+1 prefetched via global_load_lds into the alternate LDS buffer while
// computing tile k.
template<int MT>
__global__ __launch_bounds__(256) void mfma_gemm(
    const bf16* __restrict__ A, const bf16* __restrict__ Bt,
    const float* __restrict__ bias, const float* __restrict__ resid,
    void* __restrict__ Cout, int M, int N, int K, int act, int out_bf16,
    int qkvmode, bf16* __restrict__ qhg, bf16* __restrict__ khg, bf16* __restrict__ vtg)
{
    constexpr int MFRAG = MT / 32;           // m-fragments per wave
    __shared__ bf16 As[2][MT * 32];
    __shared__ bf16 Bs[2][128 * 32];
    int tid = threadIdx.x;
    int row0 = blockIdx.y * MT, col0 = blockIdx.x * 128;
    int wave = tid >> 6, lane = tid & 63;
    int wm = (wave >> 1) * (MT / 2), wn = (wave & 1) * 64;
    int l16 = lane & 15, quad = lane >> 4;

    int srow  = tid >> 2;
    int skoff = (tid & 3) * 8;

    const bf16* gA0 = A  + (size_t)(row0 + srow)      * K + skoff;
    const bf16* gA1 = A  + (size_t)(row0 + 64 + srow) * K + skoff;  // MT==128 only
    const bf16* gB0 = Bt + (size_t)(col0 + srow)      * K + skoff;
    const bf16* gB1 = Bt + (size_t)(col0 + 64 + srow) * K + skoff;

    auto stage = [&](int k0, int buf) {
        gload16(gA0 + k0, &As[buf][tid * 8]);
        if (MT == 128) gload16(gA1 + k0, &As[buf][2048 + tid * 8]);
        gload16(gB0 + k0, &Bs[buf][tid * 8]);
        gload16(gB1 + k0, &Bs[buf][2048 + tid * 8]);
    };

    floatx4 acc[MFRAG][4] = {};

    stage(0, 0);
    int cur = 0;
    for (int k0 = 0; k0 < K; k0 += 32) {
        __syncthreads();                       // buf[cur] staged; all readers done w/ alt
        if (k0 + 32 < K) stage(k0 + 32, cur ^ 1);
        bf16x8 af[MFRAG], bfr[4];
        #pragma unroll
        for (int mt = 0; mt < MFRAG; mt++)
            af[mt] = *(const bf16x8*)&As[cur][(wm + mt * 16 + l16) * 32 + quad * 8];
        #pragma unroll
        for (int nt = 0; nt < 4; nt++)
            bfr[nt] = *(const bf16x8*)&Bs[cur][(wn + nt * 16 + l16) * 32 + quad * 8];
        #pragma unroll
        for (int mt = 0; mt < MFRAG; mt++)
            #pragma unroll
            for (int nt = 0; nt < 4; nt++)
                acc[mt][nt] = __builtin_amdgcn_mfma_f32_16x16x32_bf16(
                    af[mt], bfr[nt], acc[mt][nt], 0, 0, 0);
        cur ^= 1;
    }

    if (qkvmode) {
        #pragma unroll
        for (int mt = 0; mt < MFRAG; mt++) {
            int rbase = row0 + wm + mt * 16 + quad * 4;
            int bq_ = rbase >> 10, sb = rbase & 1023;
            #pragma unroll
            for (int nt = 0; nt < 4; nt++) {
                int col = col0 + wn + nt * 16 + l16;
                float bcol = bias[col];
                if (col < DD) {
                    int hh = col >> 6, e = col & 63;
                    bf16* base = qhg + (((size_t)bq_ * HH + hh) * SS + sb) * 64 + e;
                    #pragma unroll
                    for (int r = 0; r < 4; r++)
                        base[(size_t)r * 64] = __float2bfloat16(acc[mt][nt][r] + bcol);
                } else if (col < 2 * DD) {
                    int cc = col - DD, hh = cc >> 6, e = cc & 63;
                    bf16* base = khg + (((size_t)bq_ * HH + hh) * SS) * 64;
                    #pragma unroll
                    for (int r = 0; r < 4; r++) {
                        int s = sb + r;
                        int pos = (((e >> 3) ^ (s & 7)) << 3) | (e & 7);
                        base[(size_t)s * 64 + pos] = __float2bfloat16(acc[mt][nt][r] + bcol);
                    }
                } else {
                    int cc = col - 2 * DD, hh = cc >> 6, e = cc & 63;
                    int c_t = sb >> 3;
                    int sc = (c_t & ~7) | ((c_t & 7) ^ (e & 7));
                    size_t off = (((size_t)bq_ * HH + hh) * 64 + e) * SS + sc * 8 + (sb & 7);
                    ushort4 pk;
                    pk.x = f2bfbits(acc[mt][nt][0] + bcol);
                    pk.y = f2bfbits(acc[mt][nt][1] + bcol);
                    pk.z = f2bfbits(acc[mt][nt][2] + bcol);
                    pk.w = f2bfbits(acc[mt][nt][3] + bcol);
                    *(ushort4*)&vtg[off] = pk;
                }
            }
        }
        return;
    }

    #pragma unroll
    for (int mt = 0; mt < MFRAG; mt++) {
        int rbase = row0 + wm + mt * 16 + quad * 4;
        #pragma unroll
        for (int nt = 0; nt < 4; nt++) {
            int col = col0 + wn + nt * 16 + l16;
            float bcol = bias[col];
            #pragma unroll
            for (int r = 0; r < 4; r++) {
                int row = rbase + r;
                float v = acc[mt][nt][r] + bcol;
                if (act) v = gelu_exact(v);
                if (resid) v += resid[(size_t)row * N + col];
                if (out_bf16) ((bf16*)Cout)[(size_t)row * N + col] = __float2bfloat16(v);
                else          ((float*)Cout)[(size_t)row * N + col] = v;
            }
        }
    }
}

// ---------------- MFMA flash attention, double-buffered K/V ------------------------
// Block: 128 q-rows of one (b,h); 4 waves x 32 rows. K/V staged 64-token tiles.
// qh [bh][s][64] plain; kh [bh][s][64] chunk-swizzled; vT [bh][e][1024] chunk-swizzled.
__global__ __launch_bounds__(256) void attn_mfma(
    const bf16* __restrict__ qh, const bf16* __restrict__ kh,
    const bf16* __restrict__ vT, bf16* __restrict__ ao)
{
    __shared__ bf16 Ks[2][64 * 64];
    __shared__ bf16 Vs[2][64 * 64];
    __shared__ bf16 Ps[128 * 64];

    int tid = threadIdx.x;
    int wave = tid >> 6, lane = tid & 63;
    int l16 = lane & 15, quad = lane >> 4;
    int b = blockIdx.z, h = blockIdx.y;
    int bh = b * HH + h;
    int s0 = blockIdx.x * 128;
    int wm = wave * 32;

    const bf16* qbase = qh + ((size_t)bh * SS) * HDD;
    const bf16* kbase = kh + ((size_t)bh * SS) * HDD;
    const bf16* vbase = vT + ((size_t)bh * HDD) * SS;

    auto stage = [&](int t0, int buf) {
        #pragma unroll
        for (int i = 0; i < 2; i++) {
            int c = tid + i * 256;
            gload16(kbase + (size_t)t0 * 64 + c * 8, &Ks[buf][c * 8]);
            gload16(vbase + (size_t)(c >> 3) * SS + t0 + (c & 7) * 8, &Vs[buf][c * 8]);
        }
    };

    // Q fragments, held in registers for the whole K-loop
    bf16x8 qf[2][2];
    #pragma unroll
    for (int mt = 0; mt < 2; mt++)
        #pragma unroll
        for (int ks = 0; ks < 2; ks++)
            qf[mt][ks] = *(const bf16x8*)(qbase +
                (size_t)(s0 + wm + mt * 16 + l16) * HDD + ks * 32 + quad * 8);

    floatx4 oacc[2][4] = {};
    float mrow[2][4], lrow[2][4];
    #pragma unroll
    for (int mt = 0; mt < 2; mt++)
        #pragma unroll
        for (int r = 0; r < 4; r++) { mrow[mt][r] = -INFINITY; lrow[mt][r] = 0.0f; }

    stage(0, 0);
    int cur = 0;
    for (int t0 = 0; t0 < SS; t0 += 64) {
        __syncthreads();                    // buf[cur] staged; all readers done w/ alt
        if (t0 + 64 < SS) stage(t0 + 64, cur ^ 1);

        // ---- S = Q K^T (32x64 per wave) ----
        floatx4 sacc[2][4] = {};
        #pragma unroll
        for (int nt = 0; nt < 4; nt++) {
            int t = nt * 16 + l16;
            #pragma unroll
            for (int ks = 0; ks < 2; ks++) {
                int pos = (quad + 4 * ks) ^ (t & 7);
                bf16x8 bfr = *(const bf16x8*)(&Ks[cur][t * 64 + pos * 8]);
                #pragma unroll
                for (int mt = 0; mt < 2; mt++)
                    sacc[mt][nt] = __builtin_amdgcn_mfma_f32_16x16x32_bf16(
                        qf[mt][ks], bfr, sacc[mt][nt], 0, 0, 0);
            }
        }

        // ---- online softmax + P->LDS ----
        #pragma unroll
        for (int mt = 0; mt < 2; mt++) {
            #pragma unroll
            for (int r = 0; r < 4; r++) {
                float sv0 = sacc[mt][0][r], sv1 = sacc[mt][1][r];
                float sv2 = sacc[mt][2][r], sv3 = sacc[mt][3][r];
                float mx = fmaxf(fmaxf(sv0, sv1), fmaxf(sv2, sv3));
                #pragma unroll
                for (int d = 1; d < 16; d <<= 1) mx = fmaxf(mx, __shfl_xor(mx, d, 64));
                float mnew = fmaxf(mrow[mt][r], mx);
                float corr = __expf(mrow[mt][r] - mnew);
                float p0 = __expf(sv0 - mnew), p1 = __expf(sv1 - mnew);
                float p2 = __expf(sv2 - mnew), p3 = __expf(sv3 - mnew);
                float psum = p0 + p1 + p2 + p3;
                #pragma unroll
                for (int d = 1; d < 16; d <<= 1) psum += __shfl_xor(psum, d, 64);
                lrow[mt][r] = lrow[mt][r] * corr + psum;
                mrow[mt][r] = mnew;
                #pragma unroll
                for (int nte = 0; nte < 4; nte++) oacc[mt][nte][r] *= corr;
                int row = wm + mt * 16 + quad * 4 + r;
                int r7 = row & 7;
                float pv[4] = {p0, p1, p2, p3};
                #pragma unroll
                for (int nt = 0; nt < 4; nt++) {
                    int col = nt * 16 + l16;
                    int pos = (((col >> 3) ^ r7) << 3) | (col & 7);
                    Ps[row * 64 + pos] = __float2bfloat16(pv[nt]);
                }
            }
        }

        // ---- O += P V (32x64 per wave; Ps region private to wave) ----
        #pragma unroll
        for (int mt = 0; mt < 2; mt++) {
            int prow = wm + mt * 16 + l16;
            #pragma unroll
            for (int ks = 0; ks < 2; ks++) {
                int pos = (quad + 4 * ks) ^ (prow & 7);
                bf16x8 pf = *(const bf16x8*)(Ps + prow * 64 + pos * 8);
                #pragma unroll
                for (int nte = 0; nte < 4; nte++) {
                    int e = nte * 16 + l16;
                    int vpos = (quad + 4 * ks) ^ (e & 7);
                    bf16x8 vf = *(const bf16x8*)(&Vs[cur][e * 64 + vpos * 8]);
                    oacc[mt][nte] = __builtin_amdgcn_mfma_f32_16x16x32_bf16(
                        pf, vf, oacc[mt][nte], 0, 0, 0);
                }
            }
        }
        cur ^= 1;
    }

    // ---- epilogue: O /= l, write bf16 [row][768] ----
    #pragma unroll
    for (int mt = 0; mt < 2; mt++) {
        #pragma unroll
        for (int r = 0; r < 4; r++) {
            int srow = s0 + wm + mt * 16 + quad * 4 + r;
            float invl = 1.0f / lrow[mt][r];
            bf16* op = ao + ((size_t)b * SS + srow) * DD + h * HDD;
            #pragma unroll
            for (int nte = 0; nte < 4; nte++)
                op[nte * 16 + l16] = __float2bfloat16(oacc[mt][nte][r] * invl);
        }
    }
}

// -----------------------------------------------------------------------------------
extern "C" void kernel_launch(void* const* d_in, const int* in_sizes, int n_in,
                              void* d_out, int out_size, void* d_ws, size_t ws_size,
                              hipStream_t stream)
{
    (void)in_sizes; (void)n_in; (void)out_size; (void)ws_size;
    const float* x    = (const float*)d_in[0];
    const float* ln1w = (const float*)d_in[1];
    const float* ln1b = (const float*)d_in[2];
    const float* Wq   = (const float*)d_in[3];
    const float* bq   = (const float*)d_in[4];
    const float* Wk   = (const float*)d_in[5];
    const float* bk   = (const float*)d_in[6];
    const float* Wv   = (const float*)d_in[7];
    const float* bv   = (const float*)d_in[8];
    const float* Wp   = (const float*)d_in[9];
    const float* bp   = (const float*)d_in[10];
    const float* ln2w = (const float*)d_in[11];
    const float* ln2b = (const float*)d_in[12];
    const float* W1   = (const float*)d_in[13];
    const float* b1   = (const float*)d_in[14];
    const float* W2   = (const float*)d_in[15];
    const float* b2   = (const float*)d_in[16];
    float* out = (float*)d_out;

    char* p = (char*)d_ws;
    auto alloc = [&](size_t bytes) { char* r = p; p += (bytes + 255) & ~255ull; return r; };
    bf16*  Wqkvt = (bf16*)alloc((size_t)QKVN * DD * 2);
    bf16*  Wpt   = (bf16*)alloc((size_t)DD * DD * 2);
    bf16*  W1t   = (bf16*)alloc((size_t)FFF * DD * 2);
    bf16*  W2t   = (bf16*)alloc((size_t)DD * FFF * 2);
    float* bqkv  = (float*)alloc((size_t)QKVN * 4);
    bf16*  yb    = (bf16*)alloc((size_t)NROW * DD * 2);
    char*  dynr  = alloc((size_t)NROW * DD * 2 + 3 * ((size_t)NROW * DD * 2));
    bf16*  aob   = (bf16*)dynr;                                // [row][768]
    bf16*  qhb   = (bf16*)(dynr + (size_t)NROW * DD * 2);      // [bh][s][64]
    bf16*  khb   = qhb + (size_t)NROW * DD;                    // swizzled
    bf16*  vtb   = khb + (size_t)NROW * DD;                    // [bh][e][1024] swizzled
    bf16*  hb    = (bf16*)dynr;   // FF intermediate (50MB) reuses aob+qkv region

    transpose_cast<<<dim3(DD/32, DD/32),  256, 0, stream>>>(Wq, Wqkvt,            DD, DD, 1);
    transpose_cast<<<dim3(DD/32, DD/32),  256, 0, stream>>>(Wk, Wqkvt + DD*DD,    DD, DD, 1);
    transpose_cast<<<dim3(DD/32, DD/32),  256, 0, stream>>>(Wv, Wqkvt + 2*DD*DD,  DD, DD, 1);
    transpose_cast<<<dim3(DD/32, DD/32),  256, 0, stream>>>(Wp, Wpt,              DD, DD, 0);
    transpose_cast<<<dim3(DD/32, FFF/32), 256, 0, stream>>>(W1, W1t,              DD, FFF, 0);
    transpose_cast<<<dim3(FFF/32, DD/32), 256, 0, stream>>>(W2, W2t,              FFF, DD, 0);
    concat_bias<<<3, 256, 0, stream>>>(bq, bk, bv, bqkv);

    ln_kernel<<<NROW, 256, 0, stream>>>(x, ln1w, ln1b, yb);

    // fused QKV GEMM with head-separating scatter epilogue
    mfma_gemm<128><<<dim3(QKVN/128, NROW/128), 256, 0, stream>>>(
        yb, Wqkvt, bqkv, nullptr, nullptr, NROW, QKVN, DD, 0, 0, 1, qhb, khb, vtb);

    attn_mfma<<<dim3(SS/128, HH, BB), 256, 0, stream>>>(qhb, khb, vtb, aob);

    // projection + GELU + residual(x) -> out fp32   (N=768: 64-row tiles, 768 blocks)
    mfma_gemm<64><<<dim3(DD/128, NROW/64), 256, 0, stream>>>(
        aob, Wpt, bp, x, out, NROW, DD, DD, 1, 0, 0, nullptr, nullptr, nullptr);

    ln_kernel<<<NROW, 256, 0, stream>>>(out, ln2w, ln2b, yb);

    // FF1 + GELU -> hb bf16
    mfma_gemm<128><<<dim3(FFF/128, NROW/128), 256, 0, stream>>>(
        yb, W1t, b1, nullptr, hb, NROW, FFF, DD, 1, 1, 0, nullptr, nullptr, nullptr);

    // FF2 + GELU + residual(out) -> out fp32        (N=768: 64-row tiles, 768 blocks)
    mfma_gemm<64><<<dim3(DD/128, NROW/64), 256, 0, stream>>>(
        hb, W2t, b2, out, out, NROW, DD, FFF, 1, 0, 0, nullptr, nullptr, nullptr);
}

// Round 5
// 452.327 us; speedup vs baseline: 7.3062x; 1.0948x over previous
//
#include <hip/hip_runtime.h>
#include <hip/hip_bf16.h>
#include <math.h>

#define BB 8
#define SS 1024
#define DD 768
#define HH 12
#define HDD 64
#define FFF 3072
#define NROW (BB*SS)
#define QKVN (3*DD)

typedef __hip_bfloat16 bf16;
typedef __bf16 bf16x8 __attribute__((ext_vector_type(8)));
typedef float floatx4 __attribute__((ext_vector_type(4)));

__device__ __forceinline__ float gelu_exact(float t) {
    return 0.5f * t * (1.0f + erff(t * 0.70710678118654752f));
}

__device__ __forceinline__ unsigned short f2bfbits(float f) {
    bf16 h = __float2bfloat16(f);
    return __builtin_bit_cast(unsigned short, h);
}

__device__ __forceinline__ void gload16(const void* g, void* l) {
    __builtin_amdgcn_global_load_lds(
        (const __attribute__((address_space(1))) unsigned int*)g,
        (__attribute__((address_space(3))) unsigned int*)l, 16, 0, 0);
}

// ---------------- LayerNorm: fp32 in, bf16 out, one block per row ----------------
__global__ __launch_bounds__(256) void ln_kernel(const float* __restrict__ x,
                                                 const float* __restrict__ w,
                                                 const float* __restrict__ b,
                                                 bf16* __restrict__ y) {
    int row = blockIdx.x;
    const float* xr = x + (size_t)row * DD;
    bf16* yr = y + (size_t)row * DD;
    int tid = threadIdx.x;
    float v0 = xr[tid], v1 = xr[tid + 256], v2 = xr[tid + 512];
    __shared__ float red[256], red2[256];
    red[tid]  = v0 + v1 + v2;
    red2[tid] = v0*v0 + v1*v1 + v2*v2;
    __syncthreads();
    for (int off = 128; off > 0; off >>= 1) {
        if (tid < off) { red[tid] += red[tid+off]; red2[tid] += red2[tid+off]; }
        __syncthreads();
    }
    float mu  = red[0] * (1.0f / DD);
    float var = red2[0] * (1.0f / DD) - mu * mu;
    float inv = rsqrtf(var + 1e-5f);
    yr[tid]       = __float2bfloat16((v0 - mu) * inv * w[tid]       + b[tid]);
    yr[tid + 256] = __float2bfloat16((v1 - mu) * inv * w[tid + 256] + b[tid + 256]);
    yr[tid + 512] = __float2bfloat16((v2 - mu) * inv * w[tid + 512] + b[tid + 512]);
}

// ------------- transpose+cast: src fp32 [K,N] (or headed [H][K][64]) -> bf16 [N,K]
__global__ __launch_bounds__(256) void transpose_cast(
    const float* __restrict__ src, bf16* __restrict__ dst, int K, int N, int hmode)
{
    __shared__ float t[32][33];
    int k0 = blockIdx.x * 32, n0 = blockIdx.y * 32;
    int tx = threadIdx.x & 31, ty4 = threadIdx.x >> 5;
    #pragma unroll
    for (int i = 0; i < 4; i++) {
        int k = k0 + ty4 * 4 + i;
        int n = n0 + tx;
        size_t si = hmode ? ((size_t)(n >> 6) * K * 64 + (size_t)k * 64 + (n & 63))
                          : ((size_t)k * N + n);
        t[ty4 * 4 + i][tx] = src[si];
    }
    __syncthreads();
    #pragma unroll
    for (int i = 0; i < 4; i++) {
        int n = n0 + ty4 * 4 + i;
        int k = k0 + tx;
        dst[(size_t)n * K + k] = __float2bfloat16(t[tx][ty4 * 4 + i]);
    }
}

__global__ void concat_bias(const float* __restrict__ bq, const float* __restrict__ bk,
                            const float* __restrict__ bv, float* __restrict__ dst) {
    int i = blockIdx.x * 256 + threadIdx.x;
    if (i < DD) { dst[i] = bq[i]; dst[DD + i] = bk[i]; dst[2 * DD + i] = bv[i]; }
}

// ---------------- MFMA bf16 GEMM, double-buffered: C = epi(A @ Bt^T) ---------------
template<int MT>
__global__ __launch_bounds__(256) void mfma_gemm(
    const bf16* __restrict__ A, const bf16* __restrict__ Bt,
    const float* __restrict__ bias, const float* __restrict__ resid,
    void* __restrict__ Cout, int M, int N, int K, int act, int out_bf16,
    int qkvmode, bf16* __restrict__ qhg, bf16* __restrict__ khg, bf16* __restrict__ vtg)
{
    constexpr int MFRAG = MT / 32;           // m-fragments per wave
    __shared__ bf16 As[2][MT * 32];
    __shared__ bf16 Bs[2][128 * 32];
    int tid = threadIdx.x;
    int row0 = blockIdx.y * MT, col0 = blockIdx.x * 128;
    int wave = tid >> 6, lane = tid & 63;
    int wm = (wave >> 1) * (MT / 2), wn = (wave & 1) * 64;
    int l16 = lane & 15, quad = lane >> 4;

    int srow  = tid >> 2;
    int skoff = (tid & 3) * 8;

    const bf16* gA0 = A  + (size_t)(row0 + srow)      * K + skoff;
    const bf16* gA1 = A  + (size_t)(row0 + 64 + srow) * K + skoff;  // MT==128 only
    const bf16* gB0 = Bt + (size_t)(col0 + srow)      * K + skoff;
    const bf16* gB1 = Bt + (size_t)(col0 + 64 + srow) * K + skoff;

    auto stage = [&](int k0, int buf) {
        gload16(gA0 + k0, &As[buf][tid * 8]);
        if (MT == 128) gload16(gA1 + k0, &As[buf][2048 + tid * 8]);
        gload16(gB0 + k0, &Bs[buf][tid * 8]);
        gload16(gB1 + k0, &Bs[buf][2048 + tid * 8]);
    };

    floatx4 acc[MFRAG][4] = {};

    stage(0, 0);
    int cur = 0;
    for (int k0 = 0; k0 < K; k0 += 32) {
        __syncthreads();                       // buf[cur] staged; all readers done w/ alt
        if (k0 + 32 < K) stage(k0 + 32, cur ^ 1);
        bf16x8 af[MFRAG], bfr[4];
        #pragma unroll
        for (int mt = 0; mt < MFRAG; mt++)
            af[mt] = *(const bf16x8*)&As[cur][(wm + mt * 16 + l16) * 32 + quad * 8];
        #pragma unroll
        for (int nt = 0; nt < 4; nt++)
            bfr[nt] = *(const bf16x8*)&Bs[cur][(wn + nt * 16 + l16) * 32 + quad * 8];
        #pragma unroll
        for (int mt = 0; mt < MFRAG; mt++)
            #pragma unroll
            for (int nt = 0; nt < 4; nt++)
                acc[mt][nt] = __builtin_amdgcn_mfma_f32_16x16x32_bf16(
                    af[mt], bfr[nt], acc[mt][nt], 0, 0, 0);
        cur ^= 1;
    }

    if (qkvmode) {
        #pragma unroll
        for (int mt = 0; mt < MFRAG; mt++) {
            int rbase = row0 + wm + mt * 16 + quad * 4;
            int bq_ = rbase >> 10, sb = rbase & 1023;
            #pragma unroll
            for (int nt = 0; nt < 4; nt++) {
                int col = col0 + wn + nt * 16 + l16;
                float bcol = bias[col];
                if (col < DD) {
                    int hh = col >> 6, e = col & 63;
                    bf16* base = qhg + (((size_t)bq_ * HH + hh) * SS + sb) * 64 + e;
                    #pragma unroll
                    for (int r = 0; r < 4; r++)
                        base[(size_t)r * 64] = __float2bfloat16(acc[mt][nt][r] + bcol);
                } else if (col < 2 * DD) {
                    int cc = col - DD, hh = cc >> 6, e = cc & 63;
                    bf16* base = khg + (((size_t)bq_ * HH + hh) * SS) * 64;
                    #pragma unroll
                    for (int r = 0; r < 4; r++) {
                        int s = sb + r;
                        int pos = (((e >> 3) ^ (s & 7)) << 3) | (e & 7);
                        base[(size_t)s * 64 + pos] = __float2bfloat16(acc[mt][nt][r] + bcol);
                    }
                } else {
                    int cc = col - 2 * DD, hh = cc >> 6, e = cc & 63;
                    int c_t = sb >> 3;
                    int sc = (c_t & ~7) | ((c_t & 7) ^ (e & 7));
                    size_t off = (((size_t)bq_ * HH + hh) * 64 + e) * SS + sc * 8 + (sb & 7);
                    ushort4 pk;
                    pk.x = f2bfbits(acc[mt][nt][0] + bcol);
                    pk.y = f2bfbits(acc[mt][nt][1] + bcol);
                    pk.z = f2bfbits(acc[mt][nt][2] + bcol);
                    pk.w = f2bfbits(acc[mt][nt][3] + bcol);
                    *(ushort4*)&vtg[off] = pk;
                }
            }
        }
        return;
    }

    #pragma unroll
    for (int mt = 0; mt < MFRAG; mt++) {
        int rbase = row0 + wm + mt * 16 + quad * 4;
        #pragma unroll
        for (int nt = 0; nt < 4; nt++) {
            int col = col0 + wn + nt * 16 + l16;
            float bcol = bias[col];
            #pragma unroll
            for (int r = 0; r < 4; r++) {
                int row = rbase + r;
                float v = acc[mt][nt][r] + bcol;
                if (act) v = gelu_exact(v);
                if (resid) v += resid[(size_t)row * N + col];
                if (out_bf16) ((bf16*)Cout)[(size_t)row * N + col] = __float2bfloat16(v);
                else          ((float*)Cout)[(size_t)row * N + col] = v;
            }
        }
    }
}

// ---------------- MFMA flash attention, no-max softmax -----------------------------
// Scores are q.k over 64 dims (std ~2.7, |max| < ~25): exp(s) can't overflow fp32
// or bf16, and bf16 relative precision is scale-invariant, so max-subtraction is
// mathematically unnecessary. O accumulates raw sum(e^s * v); per-lane partial l
// accumulates in-register; ONE cross-lane butterfly at the epilogue.
__global__ __launch_bounds__(256) void attn_mfma(
    const bf16* __restrict__ qh, const bf16* __restrict__ kh,
    const bf16* __restrict__ vT, bf16* __restrict__ ao)
{
    __shared__ bf16 Ks[2][64 * 64];
    __shared__ bf16 Vs[2][64 * 64];
    __shared__ bf16 Ps[128 * 64];

    int tid = threadIdx.x;
    int wave = tid >> 6, lane = tid & 63;
    int l16 = lane & 15, quad = lane >> 4;
    int b = blockIdx.z, h = blockIdx.y;
    int bh = b * HH + h;
    int s0 = blockIdx.x * 128;
    int wm = wave * 32;

    const bf16* qbase = qh + ((size_t)bh * SS) * HDD;
    const bf16* kbase = kh + ((size_t)bh * SS) * HDD;
    const bf16* vbase = vT + ((size_t)bh * HDD) * SS;

    auto stage = [&](int t0, int buf) {
        #pragma unroll
        for (int i = 0; i < 2; i++) {
            int c = tid + i * 256;
            gload16(kbase + (size_t)t0 * 64 + c * 8, &Ks[buf][c * 8]);
            gload16(vbase + (size_t)(c >> 3) * SS + t0 + (c & 7) * 8, &Vs[buf][c * 8]);
        }
    };

    // Q fragments, held in registers for the whole K-loop
    bf16x8 qf[2][2];
    #pragma unroll
    for (int mt = 0; mt < 2; mt++)
        #pragma unroll
        for (int ks = 0; ks < 2; ks++)
            qf[mt][ks] = *(const bf16x8*)(qbase +
                (size_t)(s0 + wm + mt * 16 + l16) * HDD + ks * 32 + quad * 8);

    floatx4 oacc[2][4] = {};
    float lsum[2][4] = {};

    stage(0, 0);
    int cur = 0;
    for (int t0 = 0; t0 < SS; t0 += 64) {
        __syncthreads();                    // buf[cur] staged; all readers done w/ alt
        if (t0 + 64 < SS) stage(t0 + 64, cur ^ 1);

        // ---- S = Q K^T (32x64 per wave) ----
        floatx4 sacc[2][4] = {};
        #pragma unroll
        for (int nt = 0; nt < 4; nt++) {
            int t = nt * 16 + l16;
            #pragma unroll
            for (int ks = 0; ks < 2; ks++) {
                int pos = (quad + 4 * ks) ^ (t & 7);
                bf16x8 bfr = *(const bf16x8*)(&Ks[cur][t * 64 + pos * 8]);
                #pragma unroll
                for (int mt = 0; mt < 2; mt++)
                    sacc[mt][nt] = __builtin_amdgcn_mfma_f32_16x16x32_bf16(
                        qf[mt][ks], bfr, sacc[mt][nt], 0, 0, 0);
            }
        }

        // ---- P = exp(S); accumulate per-lane partial l; P->LDS (no cross-lane ops) ----
        #pragma unroll
        for (int mt = 0; mt < 2; mt++) {
            #pragma unroll
            for (int r = 0; r < 4; r++) {
                float p0 = __expf(sacc[mt][0][r]);
                float p1 = __expf(sacc[mt][1][r]);
                float p2 = __expf(sacc[mt][2][r]);
                float p3 = __expf(sacc[mt][3][r]);
                lsum[mt][r] += (p0 + p1) + (p2 + p3);
                int row = wm + mt * 16 + quad * 4 + r;
                int r7 = row & 7;
                float pv[4] = {p0, p1, p2, p3};
                #pragma unroll
                for (int nt = 0; nt < 4; nt++) {
                    int col = nt * 16 + l16;
                    int pos = (((col >> 3) ^ r7) << 3) | (col & 7);
                    Ps[row * 64 + pos] = __float2bfloat16(pv[nt]);
                }
            }
        }

        // ---- O += P V (32x64 per wave; Ps region private to wave) ----
        #pragma unroll
        for (int mt = 0; mt < 2; mt++) {
            int prow = wm + mt * 16 + l16;
            #pragma unroll
            for (int ks = 0; ks < 2; ks++) {
                int pos = (quad + 4 * ks) ^ (prow & 7);
                bf16x8 pf = *(const bf16x8*)(Ps + prow * 64 + pos * 8);
                #pragma unroll
                for (int nte = 0; nte < 4; nte++) {
                    int e = nte * 16 + l16;
                    int vpos = (quad + 4 * ks) ^ (e & 7);
                    bf16x8 vf = *(const bf16x8*)(&Vs[cur][e * 64 + vpos * 8]);
                    oacc[mt][nte] = __builtin_amdgcn_mfma_f32_16x16x32_bf16(
                        pf, vf, oacc[mt][nte], 0, 0, 0);
                }
            }
        }
        cur ^= 1;
    }

    // ---- epilogue: reduce l across the 16 lanes of each row group, O /= l ----
    #pragma unroll
    for (int mt = 0; mt < 2; mt++) {
        #pragma unroll
        for (int r = 0; r < 4; r++) {
            float l = lsum[mt][r];
            #pragma unroll
            for (int d = 1; d < 16; d <<= 1) l += __shfl_xor(l, d, 64);
            float invl = 1.0f / l;
            int srow = s0 + wm + mt * 16 + quad * 4 + r;
            bf16* op = ao + ((size_t)b * SS + srow) * DD + h * HDD;
            #pragma unroll
            for (int nte = 0; nte < 4; nte++)
                op[nte * 16 + l16] = __float2bfloat16(oacc[mt][nte][r] * invl);
        }
    }
}

// -----------------------------------------------------------------------------------
extern "C" void kernel_launch(void* const* d_in, const int* in_sizes, int n_in,
                              void* d_out, int out_size, void* d_ws, size_t ws_size,
                              hipStream_t stream)
{
    (void)in_sizes; (void)n_in; (void)out_size; (void)ws_size;
    const float* x    = (const float*)d_in[0];
    const float* ln1w = (const float*)d_in[1];
    const float* ln1b = (const float*)d_in[2];
    const float* Wq   = (const float*)d_in[3];
    const float* bq   = (const float*)d_in[4];
    const float* Wk   = (const float*)d_in[5];
    const float* bk   = (const float*)d_in[6];
    const float* Wv   = (const float*)d_in[7];
    const float* bv   = (const float*)d_in[8];
    const float* Wp   = (const float*)d_in[9];
    const float* bp   = (const float*)d_in[10];
    const float* ln2w = (const float*)d_in[11];
    const float* ln2b = (const float*)d_in[12];
    const float* W1   = (const float*)d_in[13];
    const float* b1   = (const float*)d_in[14];
    const float* W2   = (const float*)d_in[15];
    const float* b2   = (const float*)d_in[16];
    float* out = (float*)d_out;

    char* p = (char*)d_ws;
    auto alloc = [&](size_t bytes) { char* r = p; p += (bytes + 255) & ~255ull; return r; };
    bf16*  Wqkvt = (bf16*)alloc((size_t)QKVN * DD * 2);
    bf16*  Wpt   = (bf16*)alloc((size_t)DD * DD * 2);
    bf16*  W1t   = (bf16*)alloc((size_t)FFF * DD * 2);
    bf16*  W2t   = (bf16*)alloc((size_t)DD * FFF * 2);
    float* bqkv  = (float*)alloc((size_t)QKVN * 4);
    bf16*  yb    = (bf16*)alloc((size_t)NROW * DD * 2);
    char*  dynr  = alloc((size_t)NROW * DD * 2 + 3 * ((size_t)NROW * DD * 2));
    bf16*  aob   = (bf16*)dynr;                                // [row][768]
    bf16*  qhb   = (bf16*)(dynr + (size_t)NROW * DD * 2);      // [bh][s][64]
    bf16*  khb   = qhb + (size_t)NROW * DD;                    // swizzled
    bf16*  vtb   = khb + (size_t)NROW * DD;                    // [bh][e][1024] swizzled
    bf16*  hb    = (bf16*)dynr;   // FF intermediate (50MB) reuses aob+qkv region

    transpose_cast<<<dim3(DD/32, DD/32),  256, 0, stream>>>(Wq, Wqkvt,            DD, DD, 1);
    transpose_cast<<<dim3(DD/32, DD/32),  256, 0, stream>>>(Wk, Wqkvt + DD*DD,    DD, DD, 1);
    transpose_cast<<<dim3(DD/32, DD/32),  256, 0, stream>>>(Wv, Wqkvt + 2*DD*DD,  DD, DD, 1);
    transpose_cast<<<dim3(DD/32, DD/32),  256, 0, stream>>>(Wp, Wpt,              DD, DD, 0);
    transpose_cast<<<dim3(DD/32, FFF/32), 256, 0, stream>>>(W1, W1t,              DD, FFF, 0);
    transpose_cast<<<dim3(FFF/32, DD/32), 256, 0, stream>>>(W2, W2t,              FFF, DD, 0);
    concat_bias<<<3, 256, 0, stream>>>(bq, bk, bv, bqkv);

    ln_kernel<<<NROW, 256, 0, stream>>>(x, ln1w, ln1b, yb);

    // fused QKV GEMM with head-separating scatter epilogue
    mfma_gemm<128><<<dim3(QKVN/128, NROW/128), 256, 0, stream>>>(
        yb, Wqkvt, bqkv, nullptr, nullptr, NROW, QKVN, DD, 0, 0, 1, qhb, khb, vtb);

    attn_mfma<<<dim3(SS/128, HH, BB), 256, 0, stream>>>(qhb, khb, vtb, aob);

    // projection + GELU + residual(x) -> out fp32   (N=768: 64-row tiles, 768 blocks)
    mfma_gemm<64><<<dim3(DD/128, NROW/64), 256, 0, stream>>>(
        aob, Wpt, bp, x, out, NROW, DD, DD, 1, 0, 0, nullptr, nullptr, nullptr);

    ln_kernel<<<NROW, 256, 0, stream>>>(out, ln2w, ln2b, yb);

    // FF1 + GELU -> hb bf16
    mfma_gemm<128><<<dim3(FFF/128, NROW/128), 256, 0, stream>>>(
        yb, W1t, b1, nullptr, hb, NROW, FFF, DD, 1, 1, 0, nullptr, nullptr, nullptr);

    // FF2 + GELU + residual(out) -> out fp32        (N=768: 64-row tiles, 768 blocks)
    mfma_gemm<64><<<dim3(DD/128, NROW/64), 256, 0, stream>>>(
        hb, W2t, b2, out, out, NROW, DD, FFF, 1, 0, 0, nullptr, nullptr, nullptr);
}

// Round 6
// 441.451 us; speedup vs baseline: 7.4862x; 1.0246x over previous
//
#include <hip/hip_runtime.h>
#include <hip/hip_bf16.h>
#include <math.h>

#define BB 8
#define SS 1024
#define DD 768
#define HH 12
#define HDD 64
#define FFF 3072
#define NROW (BB*SS)
#define QKVN (3*DD)

typedef __hip_bfloat16 bf16;
typedef __bf16 bf16x8 __attribute__((ext_vector_type(8)));
typedef float floatx4 __attribute__((ext_vector_type(4)));

__device__ __forceinline__ float gelu_exact(float t) {
    return 0.5f * t * (1.0f + erff(t * 0.70710678118654752f));
}

__device__ __forceinline__ unsigned short f2bfbits(float f) {
    bf16 h = __float2bfloat16(f);
    return __builtin_bit_cast(unsigned short, h);
}

__device__ __forceinline__ void gload16(const void* g, void* l) {
    __builtin_amdgcn_global_load_lds(
        (const __attribute__((address_space(1))) unsigned int*)g,
        (__attribute__((address_space(3))) unsigned int*)l, 16, 0, 0);
}

// ---------------- LayerNorm: fp32 in, bf16 out, one block per row ----------------
__global__ __launch_bounds__(256) void ln_kernel(const float* __restrict__ x,
                                                 const float* __restrict__ w,
                                                 const float* __restrict__ b,
                                                 bf16* __restrict__ y) {
    int row = blockIdx.x;
    const float* xr = x + (size_t)row * DD;
    bf16* yr = y + (size_t)row * DD;
    int tid = threadIdx.x;
    float v0 = xr[tid], v1 = xr[tid + 256], v2 = xr[tid + 512];
    __shared__ float red[256], red2[256];
    red[tid]  = v0 + v1 + v2;
    red2[tid] = v0*v0 + v1*v1 + v2*v2;
    __syncthreads();
    for (int off = 128; off > 0; off >>= 1) {
        if (tid < off) { red[tid] += red[tid+off]; red2[tid] += red2[tid+off]; }
        __syncthreads();
    }
    float mu  = red[0] * (1.0f / DD);
    float var = red2[0] * (1.0f / DD) - mu * mu;
    float inv = rsqrtf(var + 1e-5f);
    yr[tid]       = __float2bfloat16((v0 - mu) * inv * w[tid]       + b[tid]);
    yr[tid + 256] = __float2bfloat16((v1 - mu) * inv * w[tid + 256] + b[tid + 256]);
    yr[tid + 512] = __float2bfloat16((v2 - mu) * inv * w[tid + 512] + b[tid + 512]);
}

// ------------- transpose+cast: src fp32 [K,N] (or headed [H][K][64]) -> bf16 [N,K]
__global__ __launch_bounds__(256) void transpose_cast(
    const float* __restrict__ src, bf16* __restrict__ dst, int K, int N, int hmode)
{
    __shared__ float t[32][33];
    int k0 = blockIdx.x * 32, n0 = blockIdx.y * 32;
    int tx = threadIdx.x & 31, ty4 = threadIdx.x >> 5;
    #pragma unroll
    for (int i = 0; i < 4; i++) {
        int k = k0 + ty4 * 4 + i;
        int n = n0 + tx;
        size_t si = hmode ? ((size_t)(n >> 6) * K * 64 + (size_t)k * 64 + (n & 63))
                          : ((size_t)k * N + n);
        t[ty4 * 4 + i][tx] = src[si];
    }
    __syncthreads();
    #pragma unroll
    for (int i = 0; i < 4; i++) {
        int n = n0 + ty4 * 4 + i;
        int k = k0 + tx;
        dst[(size_t)n * K + k] = __float2bfloat16(t[tx][ty4 * 4 + i]);
    }
}

__global__ void concat_bias(const float* __restrict__ bq, const float* __restrict__ bk,
                            const float* __restrict__ bv, float* __restrict__ dst) {
    int i = blockIdx.x * 256 + threadIdx.x;
    if (i < DD) { dst[i] = bq[i]; dst[DD + i] = bk[i]; dst[2 * DD + i] = bv[i]; }
}

// ---------------- MFMA bf16 GEMM, double-buffered: C = epi(A @ Bt^T) ---------------
// MT = rows/block; KH = 32-k sub-blocks per barrier (BK = 32*KH).
// LDS tiles are chunk-XOR-swizzled (pos = chunk ^ ((row>>1)&3)) so fragment reads
// are bank-conflict-free; swizzle is baked into the GLOBAL fetch address (LDS dest
// of global_load_lds is fixed at base+tid*16).
template<int MT, int KH>
__global__ __launch_bounds__(256) void mfma_gemm(
    const bf16* __restrict__ A, const bf16* __restrict__ Bt,
    const float* __restrict__ bias, const float* __restrict__ resid,
    void* __restrict__ Cout, int M, int N, int K, int act, int out_bf16,
    int qkvmode, bf16* __restrict__ qhg, bf16* __restrict__ khg, bf16* __restrict__ vtg)
{
    constexpr int MFRAG = MT / 32;           // m-fragments per wave
    constexpr int ACH = MT * 4;              // A chunks per 32-k half
    __shared__ bf16 As[2][KH * MT * 32];
    __shared__ bf16 Bs[2][KH * 128 * 32];
    int tid = threadIdx.x;
    int row0 = blockIdx.y * MT, col0 = blockIdx.x * 128;
    int wave = tid >> 6, lane = tid & 63;
    int wm = (wave >> 1) * (MT / 2), wn = (wave & 1) * 64;
    int l16 = lane & 15, quad = lane >> 4;

    auto stage = [&](int k0, int buf) {
        #pragma unroll
        for (int i = 0; i < ACH * KH / 256; i++) {
            int c = tid + i * 256;
            int half = c / ACH, rem = c % ACH;
            int r = rem >> 2, pos = rem & 3;
            int ksw = k0 + half * 32 + ((pos ^ ((r >> 1) & 3)) << 3);
            gload16(A + (size_t)(row0 + r) * K + ksw, &As[buf][c * 8]);
        }
        #pragma unroll
        for (int i = 0; i < 2 * KH; i++) {
            int c = tid + i * 256;
            int half = c >> 9, rem = c & 511;
            int r = rem >> 2, pos = rem & 3;
            int ksw = k0 + half * 32 + ((pos ^ ((r >> 1) & 3)) << 3);
            gload16(Bt + (size_t)(col0 + r) * K + ksw, &Bs[buf][c * 8]);
        }
    };

    floatx4 acc[MFRAG][4] = {};

    stage(0, 0);
    int cur = 0;
    for (int k0 = 0; k0 < K; k0 += 32 * KH) {
        __syncthreads();                       // buf[cur] staged; all readers done w/ alt
        if (k0 + 32 * KH < K) stage(k0 + 32 * KH, cur ^ 1);
        #pragma unroll
        for (int s = 0; s < KH; s++) {
            bf16x8 af[MFRAG], bfr[4];
            #pragma unroll
            for (int mt = 0; mt < MFRAG; mt++) {
                int r = wm + mt * 16 + l16;
                int pos = quad ^ ((r >> 1) & 3);
                af[mt] = *(const bf16x8*)&As[cur][s * MT * 32 + r * 32 + pos * 8];
            }
            #pragma unroll
            for (int nt = 0; nt < 4; nt++) {
                int r = wn + nt * 16 + l16;
                int pos = quad ^ ((r >> 1) & 3);
                bfr[nt] = *(const bf16x8*)&Bs[cur][s * 4096 + r * 32 + pos * 8];
            }
            #pragma unroll
            for (int mt = 0; mt < MFRAG; mt++)
                #pragma unroll
                for (int nt = 0; nt < 4; nt++)
                    acc[mt][nt] = __builtin_amdgcn_mfma_f32_16x16x32_bf16(
                        af[mt], bfr[nt], acc[mt][nt], 0, 0, 0);
        }
        cur ^= 1;
    }

    if (qkvmode) {
        #pragma unroll
        for (int mt = 0; mt < MFRAG; mt++) {
            int rbase = row0 + wm + mt * 16 + quad * 4;
            int bq_ = rbase >> 10, sb = rbase & 1023;
            #pragma unroll
            for (int nt = 0; nt < 4; nt++) {
                int col = col0 + wn + nt * 16 + l16;
                float bcol = bias[col];
                if (col < DD) {
                    int hh = col >> 6, e = col & 63;
                    bf16* base = qhg + (((size_t)bq_ * HH + hh) * SS + sb) * 64 + e;
                    #pragma unroll
                    for (int r = 0; r < 4; r++)
                        base[(size_t)r * 64] = __float2bfloat16(acc[mt][nt][r] + bcol);
                } else if (col < 2 * DD) {
                    int cc = col - DD, hh = cc >> 6, e = cc & 63;
                    bf16* base = khg + (((size_t)bq_ * HH + hh) * SS) * 64;
                    #pragma unroll
                    for (int r = 0; r < 4; r++) {
                        int s = sb + r;
                        int pos = (((e >> 3) ^ (s & 7)) << 3) | (e & 7);
                        base[(size_t)s * 64 + pos] = __float2bfloat16(acc[mt][nt][r] + bcol);
                    }
                } else {
                    int cc = col - 2 * DD, hh = cc >> 6, e = cc & 63;
                    int c_t = sb >> 3;
                    int sc = (c_t & ~7) | ((c_t & 7) ^ (e & 7));
                    size_t off = (((size_t)bq_ * HH + hh) * 64 + e) * SS + sc * 8 + (sb & 7);
                    ushort4 pk;
                    pk.x = f2bfbits(acc[mt][nt][0] + bcol);
                    pk.y = f2bfbits(acc[mt][nt][1] + bcol);
                    pk.z = f2bfbits(acc[mt][nt][2] + bcol);
                    pk.w = f2bfbits(acc[mt][nt][3] + bcol);
                    *(ushort4*)&vtg[off] = pk;
                }
            }
        }
        return;
    }

    #pragma unroll
    for (int mt = 0; mt < MFRAG; mt++) {
        int rbase = row0 + wm + mt * 16 + quad * 4;
        #pragma unroll
        for (int nt = 0; nt < 4; nt++) {
            int col = col0 + wn + nt * 16 + l16;
            float bcol = bias[col];
            #pragma unroll
            for (int r = 0; r < 4; r++) {
                int row = rbase + r;
                float v = acc[mt][nt][r] + bcol;
                if (act) v = gelu_exact(v);
                if (resid) v += resid[(size_t)row * N + col];
                if (out_bf16) ((bf16*)Cout)[(size_t)row * N + col] = __float2bfloat16(v);
                else          ((float*)Cout)[(size_t)row * N + col] = v;
            }
        }
    }
}

// ---------------- MFMA flash attention, no-max softmax -----------------------------
__global__ __launch_bounds__(256) void attn_mfma(
    const bf16* __restrict__ qh, const bf16* __restrict__ kh,
    const bf16* __restrict__ vT, bf16* __restrict__ ao)
{
    __shared__ bf16 Ks[2][64 * 64];
    __shared__ bf16 Vs[2][64 * 64];
    __shared__ bf16 Ps[128 * 64];

    int tid = threadIdx.x;
    int wave = tid >> 6, lane = tid & 63;
    int l16 = lane & 15, quad = lane >> 4;
    int b = blockIdx.z, h = blockIdx.y;
    int bh = b * HH + h;
    int s0 = blockIdx.x * 128;
    int wm = wave * 32;

    const bf16* qbase = qh + ((size_t)bh * SS) * HDD;
    const bf16* kbase = kh + ((size_t)bh * SS) * HDD;
    const bf16* vbase = vT + ((size_t)bh * HDD) * SS;

    auto stage = [&](int t0, int buf) {
        #pragma unroll
        for (int i = 0; i < 2; i++) {
            int c = tid + i * 256;
            gload16(kbase + (size_t)t0 * 64 + c * 8, &Ks[buf][c * 8]);
            gload16(vbase + (size_t)(c >> 3) * SS + t0 + (c & 7) * 8, &Vs[buf][c * 8]);
        }
    };

    bf16x8 qf[2][2];
    #pragma unroll
    for (int mt = 0; mt < 2; mt++)
        #pragma unroll
        for (int ks = 0; ks < 2; ks++)
            qf[mt][ks] = *(const bf16x8*)(qbase +
                (size_t)(s0 + wm + mt * 16 + l16) * HDD + ks * 32 + quad * 8);

    floatx4 oacc[2][4] = {};
    float lsum[2][4] = {};

    stage(0, 0);
    int cur = 0;
    for (int t0 = 0; t0 < SS; t0 += 64) {
        __syncthreads();
        if (t0 + 64 < SS) stage(t0 + 64, cur ^ 1);

        // ---- S = Q K^T (32x64 per wave) ----
        floatx4 sacc[2][4] = {};
        #pragma unroll
        for (int nt = 0; nt < 4; nt++) {
            int t = nt * 16 + l16;
            #pragma unroll
            for (int ks = 0; ks < 2; ks++) {
                int pos = (quad + 4 * ks) ^ (t & 7);
                bf16x8 bfr = *(const bf16x8*)(&Ks[cur][t * 64 + pos * 8]);
                #pragma unroll
                for (int mt = 0; mt < 2; mt++)
                    sacc[mt][nt] = __builtin_amdgcn_mfma_f32_16x16x32_bf16(
                        qf[mt][ks], bfr, sacc[mt][nt], 0, 0, 0);
            }
        }

        // ---- P = exp(S); per-lane partial l; P->LDS ----
        #pragma unroll
        for (int mt = 0; mt < 2; mt++) {
            #pragma unroll
            for (int r = 0; r < 4; r++) {
                float p0 = __expf(sacc[mt][0][r]);
                float p1 = __expf(sacc[mt][1][r]);
                float p2 = __expf(sacc[mt][2][r]);
                float p3 = __expf(sacc[mt][3][r]);
                lsum[mt][r] += (p0 + p1) + (p2 + p3);
                int row = wm + mt * 16 + quad * 4 + r;
                int r7 = row & 7;
                float pv[4] = {p0, p1, p2, p3};
                #pragma unroll
                for (int nt = 0; nt < 4; nt++) {
                    int col = nt * 16 + l16;
                    int pos = (((col >> 3) ^ r7) << 3) | (col & 7);
                    Ps[row * 64 + pos] = __float2bfloat16(pv[nt]);
                }
            }
        }

        // ---- O += P V ----
        #pragma unroll
        for (int mt = 0; mt < 2; mt++) {
            int prow = wm + mt * 16 + l16;
            #pragma unroll
            for (int ks = 0; ks < 2; ks++) {
                int pos = (quad + 4 * ks) ^ (prow & 7);
                bf16x8 pf = *(const bf16x8*)(Ps + prow * 64 + pos * 8);
                #pragma unroll
                for (int nte = 0; nte < 4; nte++) {
                    int e = nte * 16 + l16;
                    int vpos = (quad + 4 * ks) ^ (e & 7);
                    bf16x8 vf = *(const bf16x8*)(&Vs[cur][e * 64 + vpos * 8]);
                    oacc[mt][nte] = __builtin_amdgcn_mfma_f32_16x16x32_bf16(
                        pf, vf, oacc[mt][nte], 0, 0, 0);
                }
            }
        }
        cur ^= 1;
    }

    // ---- epilogue: reduce l across 16 lanes, O /= l ----
    #pragma unroll
    for (int mt = 0; mt < 2; mt++) {
        #pragma unroll
        for (int r = 0; r < 4; r++) {
            float l = lsum[mt][r];
            #pragma unroll
            for (int d = 1; d < 16; d <<= 1) l += __shfl_xor(l, d, 64);
            float invl = 1.0f / l;
            int srow = s0 + wm + mt * 16 + quad * 4 + r;
            bf16* op = ao + ((size_t)b * SS + srow) * DD + h * HDD;
            #pragma unroll
            for (int nte = 0; nte < 4; nte++)
                op[nte * 16 + l16] = __float2bfloat16(oacc[mt][nte][r] * invl);
        }
    }
}

// -----------------------------------------------------------------------------------
extern "C" void kernel_launch(void* const* d_in, const int* in_sizes, int n_in,
                              void* d_out, int out_size, void* d_ws, size_t ws_size,
                              hipStream_t stream)
{
    (void)in_sizes; (void)n_in; (void)out_size; (void)ws_size;
    const float* x    = (const float*)d_in[0];
    const float* ln1w = (const float*)d_in[1];
    const float* ln1b = (const float*)d_in[2];
    const float* Wq   = (const float*)d_in[3];
    const float* bq   = (const float*)d_in[4];
    const float* Wk   = (const float*)d_in[5];
    const float* bk   = (const float*)d_in[6];
    const float* Wv   = (const float*)d_in[7];
    const float* bv   = (const float*)d_in[8];
    const float* Wp   = (const float*)d_in[9];
    const float* bp   = (const float*)d_in[10];
    const float* ln2w = (const float*)d_in[11];
    const float* ln2b = (const float*)d_in[12];
    const float* W1   = (const float*)d_in[13];
    const float* b1   = (const float*)d_in[14];
    const float* W2   = (const float*)d_in[15];
    const float* b2   = (const float*)d_in[16];
    float* out = (float*)d_out;

    char* p = (char*)d_ws;
    auto alloc = [&](size_t bytes) { char* r = p; p += (bytes + 255) & ~255ull; return r; };
    bf16*  Wqkvt = (bf16*)alloc((size_t)QKVN * DD * 2);
    bf16*  Wpt   = (bf16*)alloc((size_t)DD * DD * 2);
    bf16*  W1t   = (bf16*)alloc((size_t)FFF * DD * 2);
    bf16*  W2t   = (bf16*)alloc((size_t)DD * FFF * 2);
    float* bqkv  = (float*)alloc((size_t)QKVN * 4);
    bf16*  yb    = (bf16*)alloc((size_t)NROW * DD * 2);
    char*  dynr  = alloc((size_t)NROW * DD * 2 + 3 * ((size_t)NROW * DD * 2));
    bf16*  aob   = (bf16*)dynr;                                // [row][768]
    bf16*  qhb   = (bf16*)(dynr + (size_t)NROW * DD * 2);      // [bh][s][64]
    bf16*  khb   = qhb + (size_t)NROW * DD;                    // swizzled
    bf16*  vtb   = khb + (size_t)NROW * DD;                    // [bh][e][1024] swizzled
    bf16*  hb    = (bf16*)dynr;   // FF intermediate (50MB) reuses aob+qkv region

    transpose_cast<<<dim3(DD/32, DD/32),  256, 0, stream>>>(Wq, Wqkvt,            DD, DD, 1);
    transpose_cast<<<dim3(DD/32, DD/32),  256, 0, stream>>>(Wk, Wqkvt + DD*DD,    DD, DD, 1);
    transpose_cast<<<dim3(DD/32, DD/32),  256, 0, stream>>>(Wv, Wqkvt + 2*DD*DD,  DD, DD, 1);
    transpose_cast<<<dim3(DD/32, DD/32),  256, 0, stream>>>(Wp, Wpt,              DD, DD, 0);
    transpose_cast<<<dim3(DD/32, FFF/32), 256, 0, stream>>>(W1, W1t,              DD, FFF, 0);
    transpose_cast<<<dim3(FFF/32, DD/32), 256, 0, stream>>>(W2, W2t,              FFF, DD, 0);
    concat_bias<<<3, 256, 0, stream>>>(bq, bk, bv, bqkv);

    ln_kernel<<<NROW, 256, 0, stream>>>(x, ln1w, ln1b, yb);

    // fused QKV GEMM with head-separating scatter epilogue (128-tile, BK=32)
    mfma_gemm<128,1><<<dim3(QKVN/128, NROW/128), 256, 0, stream>>>(
        yb, Wqkvt, bqkv, nullptr, nullptr, NROW, QKVN, DD, 0, 0, 1, qhb, khb, vtb);

    attn_mfma<<<dim3(SS/128, HH, BB), 256, 0, stream>>>(qhb, khb, vtb, aob);

    // projection + GELU + residual(x) -> out fp32   (64-row tiles, BK=64, 768 blocks)
    mfma_gemm<64,2><<<dim3(DD/128, NROW/64), 256, 0, stream>>>(
        aob, Wpt, bp, x, out, NROW, DD, DD, 1, 0, 0, nullptr, nullptr, nullptr);

    ln_kernel<<<NROW, 256, 0, stream>>>(out, ln2w, ln2b, yb);

    // FF1 + GELU -> hb bf16   (128-tile, BK=32)
    mfma_gemm<128,1><<<dim3(FFF/128, NROW/128), 256, 0, stream>>>(
        yb, W1t, b1, nullptr, hb, NROW, FFF, DD, 1, 1, 0, nullptr, nullptr, nullptr);

    // FF2 + GELU + residual(out) -> out fp32   (64-row tiles, BK=64, 768 blocks)
    mfma_gemm<64,2><<<dim3(DD/128, NROW/64), 256, 0, stream>>>(
        hb, W2t, b2, out, out, NROW, DD, FFF, 1, 0, 0, nullptr, nullptr, nullptr);
}

// Round 7
// 425.514 us; speedup vs baseline: 7.7666x; 1.0375x over previous
//
#include <hip/hip_runtime.h>
#include <hip/hip_bf16.h>
#include <math.h>

#define BB 8
#define SS 1024
#define DD 768
#define HH 12
#define HDD 64
#define FFF 3072
#define NROW (BB*SS)
#define QKVN (3*DD)

typedef __hip_bfloat16 bf16;
typedef __bf16 bf16x8 __attribute__((ext_vector_type(8)));
typedef float floatx4 __attribute__((ext_vector_type(4)));

// tanh-form GELU: ~9 VALU ops (exp+rcp) vs ~30 for erff; max abs err ~1e-3.
__device__ __forceinline__ float gelu_fast(float x) {
    float u = x * fmaf(0.07135481627f, x * x, 1.595769122f);   // 2*0.7978845608*(x+0.044715x^3)/x
    float e = __expf(u);
    return x * e * __builtin_amdgcn_rcpf(e + 1.0f);
}

__device__ __forceinline__ unsigned short f2bfbits(float f) {
    bf16 h = __float2bfloat16(f);
    return __builtin_bit_cast(unsigned short, h);
}

__device__ __forceinline__ void gload16(const void* g, void* l) {
    __builtin_amdgcn_global_load_lds(
        (const __attribute__((address_space(1))) unsigned int*)g,
        (__attribute__((address_space(3))) unsigned int*)l, 16, 0, 0);
}

// ---------------- LayerNorm: fp32 in, bf16 out, one block per row ----------------
__global__ __launch_bounds__(256) void ln_kernel(const float* __restrict__ x,
                                                 const float* __restrict__ w,
                                                 const float* __restrict__ b,
                                                 bf16* __restrict__ y) {
    int row = blockIdx.x;
    const float* xr = x + (size_t)row * DD;
    bf16* yr = y + (size_t)row * DD;
    int tid = threadIdx.x;
    float v0 = xr[tid], v1 = xr[tid + 256], v2 = xr[tid + 512];
    __shared__ float red[256], red2[256];
    red[tid]  = v0 + v1 + v2;
    red2[tid] = v0*v0 + v1*v1 + v2*v2;
    __syncthreads();
    for (int off = 128; off > 0; off >>= 1) {
        if (tid < off) { red[tid] += red[tid+off]; red2[tid] += red2[tid+off]; }
        __syncthreads();
    }
    float mu  = red[0] * (1.0f / DD);
    float var = red2[0] * (1.0f / DD) - mu * mu;
    float inv = rsqrtf(var + 1e-5f);
    yr[tid]       = __float2bfloat16((v0 - mu) * inv * w[tid]       + b[tid]);
    yr[tid + 256] = __float2bfloat16((v1 - mu) * inv * w[tid + 256] + b[tid + 256]);
    yr[tid + 512] = __float2bfloat16((v2 - mu) * inv * w[tid + 512] + b[tid + 512]);
}

// ------------- transpose+cast: src fp32 [K,N] (or headed [H][K][64]) -> bf16 [N,K]
__global__ __launch_bounds__(256) void transpose_cast(
    const float* __restrict__ src, bf16* __restrict__ dst, int K, int N, int hmode)
{
    __shared__ float t[32][33];
    int k0 = blockIdx.x * 32, n0 = blockIdx.y * 32;
    int tx = threadIdx.x & 31, ty4 = threadIdx.x >> 5;
    #pragma unroll
    for (int i = 0; i < 4; i++) {
        int k = k0 + ty4 * 4 + i;
        int n = n0 + tx;
        size_t si = hmode ? ((size_t)(n >> 6) * K * 64 + (size_t)k * 64 + (n & 63))
                          : ((size_t)k * N + n);
        t[ty4 * 4 + i][tx] = src[si];
    }
    __syncthreads();
    #pragma unroll
    for (int i = 0; i < 4; i++) {
        int n = n0 + ty4 * 4 + i;
        int k = k0 + tx;
        dst[(size_t)n * K + k] = __float2bfloat16(t[tx][ty4 * 4 + i]);
    }
}

__global__ void concat_bias(const float* __restrict__ bq, const float* __restrict__ bk,
                            const float* __restrict__ bv, float* __restrict__ dst) {
    int i = blockIdx.x * 256 + threadIdx.x;
    if (i < DD) { dst[i] = bq[i]; dst[DD + i] = bk[i]; dst[2 * DD + i] = bv[i]; }
}

// ---------------- MFMA bf16 GEMM, double-buffered: C = epi(A @ Bt^T) ---------------
// MT = rows/block; KH = 32-k sub-blocks per barrier (BK = 32*KH).
// LDS tiles chunk-XOR-swizzled (pos = chunk ^ ((row>>1)&3)): conflict-free frag reads.
template<int MT, int KH>
__global__ __launch_bounds__(256) void mfma_gemm(
    const bf16* __restrict__ A, const bf16* __restrict__ Bt,
    const float* __restrict__ bias, const float* __restrict__ resid,
    void* __restrict__ Cout, int M, int N, int K, int act, int out_bf16,
    int qkvmode, bf16* __restrict__ qhg, bf16* __restrict__ khg, bf16* __restrict__ vtg)
{
    constexpr int MFRAG = MT / 32;           // m-fragments per wave
    constexpr int ACH = MT * 4;              // A chunks per 32-k half
    __shared__ bf16 As[2][KH * MT * 32];
    __shared__ bf16 Bs[2][KH * 128 * 32];
    int tid = threadIdx.x;
    int row0 = blockIdx.y * MT, col0 = blockIdx.x * 128;
    int wave = tid >> 6, lane = tid & 63;
    int wm = (wave >> 1) * (MT / 2), wn = (wave & 1) * 64;
    int l16 = lane & 15, quad = lane >> 4;

    auto stage = [&](int k0, int buf) {
        #pragma unroll
        for (int i = 0; i < ACH * KH / 256; i++) {
            int c = tid + i * 256;
            int half = c / ACH, rem = c % ACH;
            int r = rem >> 2, pos = rem & 3;
            int ksw = k0 + half * 32 + ((pos ^ ((r >> 1) & 3)) << 3);
            gload16(A + (size_t)(row0 + r) * K + ksw, &As[buf][c * 8]);
        }
        #pragma unroll
        for (int i = 0; i < 2 * KH; i++) {
            int c = tid + i * 256;
            int half = c >> 9, rem = c & 511;
            int r = rem >> 2, pos = rem & 3;
            int ksw = k0 + half * 32 + ((pos ^ ((r >> 1) & 3)) << 3);
            gload16(Bt + (size_t)(col0 + r) * K + ksw, &Bs[buf][c * 8]);
        }
    };

    floatx4 acc[MFRAG][4] = {};

    stage(0, 0);
    int cur = 0;
    for (int k0 = 0; k0 < K; k0 += 32 * KH) {
        __syncthreads();                       // buf[cur] staged; all readers done w/ alt
        if (k0 + 32 * KH < K) stage(k0 + 32 * KH, cur ^ 1);
        #pragma unroll
        for (int s = 0; s < KH; s++) {
            bf16x8 af[MFRAG], bfr[4];
            #pragma unroll
            for (int mt = 0; mt < MFRAG; mt++) {
                int r = wm + mt * 16 + l16;
                int pos = quad ^ ((r >> 1) & 3);
                af[mt] = *(const bf16x8*)&As[cur][s * MT * 32 + r * 32 + pos * 8];
            }
            #pragma unroll
            for (int nt = 0; nt < 4; nt++) {
                int r = wn + nt * 16 + l16;
                int pos = quad ^ ((r >> 1) & 3);
                bfr[nt] = *(const bf16x8*)&Bs[cur][s * 4096 + r * 32 + pos * 8];
            }
            #pragma unroll
            for (int mt = 0; mt < MFRAG; mt++)
                #pragma unroll
                for (int nt = 0; nt < 4; nt++)
                    acc[mt][nt] = __builtin_amdgcn_mfma_f32_16x16x32_bf16(
                        af[mt], bfr[nt], acc[mt][nt], 0, 0, 0);
        }
        cur ^= 1;
    }

    if (qkvmode) {
        #pragma unroll
        for (int mt = 0; mt < MFRAG; mt++) {
            int rbase = row0 + wm + mt * 16 + quad * 4;
            int bq_ = rbase >> 10, sb = rbase & 1023;
            #pragma unroll
            for (int nt = 0; nt < 4; nt++) {
                int col = col0 + wn + nt * 16 + l16;
                float bcol = bias[col];
                if (col < DD) {
                    int hh = col >> 6, e = col & 63;
                    bf16* base = qhg + (((size_t)bq_ * HH + hh) * SS + sb) * 64 + e;
                    #pragma unroll
                    for (int r = 0; r < 4; r++)
                        base[(size_t)r * 64] = __float2bfloat16(acc[mt][nt][r] + bcol);
                } else if (col < 2 * DD) {
                    int cc = col - DD, hh = cc >> 6, e = cc & 63;
                    bf16* base = khg + (((size_t)bq_ * HH + hh) * SS) * 64;
                    #pragma unroll
                    for (int r = 0; r < 4; r++) {
                        int s = sb + r;
                        int pos = (((e >> 3) ^ (s & 7)) << 3) | (e & 7);
                        base[(size_t)s * 64 + pos] = __float2bfloat16(acc[mt][nt][r] + bcol);
                    }
                } else {
                    int cc = col - 2 * DD, hh = cc >> 6, e = cc & 63;
                    int c_t = sb >> 3;
                    int sc = (c_t & ~7) | ((c_t & 7) ^ (e & 7));
                    size_t off = (((size_t)bq_ * HH + hh) * 64 + e) * SS + sc * 8 + (sb & 7);
                    ushort4 pk;
                    pk.x = f2bfbits(acc[mt][nt][0] + bcol);
                    pk.y = f2bfbits(acc[mt][nt][1] + bcol);
                    pk.z = f2bfbits(acc[mt][nt][2] + bcol);
                    pk.w = f2bfbits(acc[mt][nt][3] + bcol);
                    *(ushort4*)&vtg[off] = pk;
                }
            }
        }
        return;
    }

    #pragma unroll
    for (int mt = 0; mt < MFRAG; mt++) {
        int rbase = row0 + wm + mt * 16 + quad * 4;
        #pragma unroll
        for (int nt = 0; nt < 4; nt++) {
            int col = col0 + wn + nt * 16 + l16;
            float bcol = bias[col];
            #pragma unroll
            for (int r = 0; r < 4; r++) {
                int row = rbase + r;
                float v = acc[mt][nt][r] + bcol;
                if (act) v = gelu_fast(v);
                if (resid) v += resid[(size_t)row * N + col];
                if (out_bf16) ((bf16*)Cout)[(size_t)row * N + col] = __float2bfloat16(v);
                else          ((float*)Cout)[(size_t)row * N + col] = v;
            }
        }
    }
}

// ---------------- MFMA flash attention, no-max softmax -----------------------------
// 1D grid, XCD-swizzled: all 8 q-tiles of one (b,h) share linear_id%8 so KV re-reads
// hit the same XCD's L2 (12 heads x 256KB = 3MB < 4MB L2 per XCD).
__global__ __launch_bounds__(256) void attn_mfma(
    const bf16* __restrict__ qh, const bf16* __restrict__ kh,
    const bf16* __restrict__ vT, bf16* __restrict__ ao)
{
    __shared__ bf16 Ks[2][64 * 64];
    __shared__ bf16 Vs[2][64 * 64];
    __shared__ bf16 Ps[128 * 64];

    int tid = threadIdx.x;
    int wave = tid >> 6, lane = tid & 63;
    int l16 = lane & 15, quad = lane >> 4;
    int id = blockIdx.x;
    int bh = (id & 7) * 12 + ((id >> 3) >> 3);   // xcd*12 + j/8
    int b = bh / HH, h = bh % HH;
    int s0 = ((id >> 3) & 7) * 128;
    int wm = wave * 32;

    const bf16* qbase = qh + ((size_t)bh * SS) * HDD;
    const bf16* kbase = kh + ((size_t)bh * SS) * HDD;
    const bf16* vbase = vT + ((size_t)bh * HDD) * SS;

    auto stage = [&](int t0, int buf) {
        #pragma unroll
        for (int i = 0; i < 2; i++) {
            int c = tid + i * 256;
            gload16(kbase + (size_t)t0 * 64 + c * 8, &Ks[buf][c * 8]);
            gload16(vbase + (size_t)(c >> 3) * SS + t0 + (c & 7) * 8, &Vs[buf][c * 8]);
        }
    };

    bf16x8 qf[2][2];
    #pragma unroll
    for (int mt = 0; mt < 2; mt++)
        #pragma unroll
        for (int ks = 0; ks < 2; ks++)
            qf[mt][ks] = *(const bf16x8*)(qbase +
                (size_t)(s0 + wm + mt * 16 + l16) * HDD + ks * 32 + quad * 8);

    floatx4 oacc[2][4] = {};
    float lsum[2][4] = {};

    stage(0, 0);
    int cur = 0;
    for (int t0 = 0; t0 < SS; t0 += 64) {
        __syncthreads();
        if (t0 + 64 < SS) stage(t0 + 64, cur ^ 1);

        // ---- S = Q K^T (32x64 per wave) ----
        floatx4 sacc[2][4] = {};
        #pragma unroll
        for (int nt = 0; nt < 4; nt++) {
            int t = nt * 16 + l16;
            #pragma unroll
            for (int ks = 0; ks < 2; ks++) {
                int pos = (quad + 4 * ks) ^ (t & 7);
                bf16x8 bfr = *(const bf16x8*)(&Ks[cur][t * 64 + pos * 8]);
                #pragma unroll
                for (int mt = 0; mt < 2; mt++)
                    sacc[mt][nt] = __builtin_amdgcn_mfma_f32_16x16x32_bf16(
                        qf[mt][ks], bfr, sacc[mt][nt], 0, 0, 0);
            }
        }

        // ---- P = exp(S); per-lane partial l; P->LDS ----
        #pragma unroll
        for (int mt = 0; mt < 2; mt++) {
            #pragma unroll
            for (int r = 0; r < 4; r++) {
                float p0 = __expf(sacc[mt][0][r]);
                float p1 = __expf(sacc[mt][1][r]);
                float p2 = __expf(sacc[mt][2][r]);
                float p3 = __expf(sacc[mt][3][r]);
                lsum[mt][r] += (p0 + p1) + (p2 + p3);
                int row = wm + mt * 16 + quad * 4 + r;
                int r7 = row & 7;
                float pv[4] = {p0, p1, p2, p3};
                #pragma unroll
                for (int nt = 0; nt < 4; nt++) {
                    int col = nt * 16 + l16;
                    int pos = (((col >> 3) ^ r7) << 3) | (col & 7);
                    Ps[row * 64 + pos] = __float2bfloat16(pv[nt]);
                }
            }
        }

        // ---- O += P V ----
        #pragma unroll
        for (int mt = 0; mt < 2; mt++) {
            int prow = wm + mt * 16 + l16;
            #pragma unroll
            for (int ks = 0; ks < 2; ks++) {
                int pos = (quad + 4 * ks) ^ (prow & 7);
                bf16x8 pf = *(const bf16x8*)(Ps + prow * 64 + pos * 8);
                #pragma unroll
                for (int nte = 0; nte < 4; nte++) {
                    int e = nte * 16 + l16;
                    int vpos = (quad + 4 * ks) ^ (e & 7);
                    bf16x8 vf = *(const bf16x8*)(&Vs[cur][e * 64 + vpos * 8]);
                    oacc[mt][nte] = __builtin_amdgcn_mfma_f32_16x16x32_bf16(
                        pf, vf, oacc[mt][nte], 0, 0, 0);
                }
            }
        }
        cur ^= 1;
    }

    // ---- epilogue: reduce l across 16 lanes, O /= l ----
    #pragma unroll
    for (int mt = 0; mt < 2; mt++) {
        #pragma unroll
        for (int r = 0; r < 4; r++) {
            float l = lsum[mt][r];
            #pragma unroll
            for (int d = 1; d < 16; d <<= 1) l += __shfl_xor(l, d, 64);
            float invl = 1.0f / l;
            int srow = s0 + wm + mt * 16 + quad * 4 + r;
            bf16* op = ao + ((size_t)b * SS + srow) * DD + h * HDD;
            #pragma unroll
            for (int nte = 0; nte < 4; nte++)
                op[nte * 16 + l16] = __float2bfloat16(oacc[mt][nte][r] * invl);
        }
    }
}

// -----------------------------------------------------------------------------------
extern "C" void kernel_launch(void* const* d_in, const int* in_sizes, int n_in,
                              void* d_out, int out_size, void* d_ws, size_t ws_size,
                              hipStream_t stream)
{
    (void)in_sizes; (void)n_in; (void)out_size; (void)ws_size;
    const float* x    = (const float*)d_in[0];
    const float* ln1w = (const float*)d_in[1];
    const float* ln1b = (const float*)d_in[2];
    const float* Wq   = (const float*)d_in[3];
    const float* bq   = (const float*)d_in[4];
    const float* Wk   = (const float*)d_in[5];
    const float* bk   = (const float*)d_in[6];
    const float* Wv   = (const float*)d_in[7];
    const float* bv   = (const float*)d_in[8];
    const float* Wp   = (const float*)d_in[9];
    const float* bp   = (const float*)d_in[10];
    const float* ln2w = (const float*)d_in[11];
    const float* ln2b = (const float*)d_in[12];
    const float* W1   = (const float*)d_in[13];
    const float* b1   = (const float*)d_in[14];
    const float* W2   = (const float*)d_in[15];
    const float* b2   = (const float*)d_in[16];
    float* out = (float*)d_out;

    char* p = (char*)d_ws;
    auto alloc = [&](size_t bytes) { char* r = p; p += (bytes + 255) & ~255ull; return r; };
    bf16*  Wqkvt = (bf16*)alloc((size_t)QKVN * DD * 2);
    bf16*  Wpt   = (bf16*)alloc((size_t)DD * DD * 2);
    bf16*  W1t   = (bf16*)alloc((size_t)FFF * DD * 2);
    bf16*  W2t   = (bf16*)alloc((size_t)DD * FFF * 2);
    float* bqkv  = (float*)alloc((size_t)QKVN * 4);
    bf16*  yb    = (bf16*)alloc((size_t)NROW * DD * 2);
    char*  dynr  = alloc((size_t)NROW * DD * 2 + 3 * ((size_t)NROW * DD * 2));
    bf16*  aob   = (bf16*)dynr;                                // [row][768]
    bf16*  qhb   = (bf16*)(dynr + (size_t)NROW * DD * 2);      // [bh][s][64]
    bf16*  khb   = qhb + (size_t)NROW * DD;                    // swizzled
    bf16*  vtb   = khb + (size_t)NROW * DD;                    // [bh][e][1024] swizzled
    bf16*  hb    = (bf16*)dynr;   // FF intermediate (50MB) reuses aob+qkv region

    transpose_cast<<<dim3(DD/32, DD/32),  256, 0, stream>>>(Wq, Wqkvt,            DD, DD, 1);
    transpose_cast<<<dim3(DD/32, DD/32),  256, 0, stream>>>(Wk, Wqkvt + DD*DD,    DD, DD, 1);
    transpose_cast<<<dim3(DD/32, DD/32),  256, 0, stream>>>(Wv, Wqkvt + 2*DD*DD,  DD, DD, 1);
    transpose_cast<<<dim3(DD/32, DD/32),  256, 0, stream>>>(Wp, Wpt,              DD, DD, 0);
    transpose_cast<<<dim3(DD/32, FFF/32), 256, 0, stream>>>(W1, W1t,              DD, FFF, 0);
    transpose_cast<<<dim3(FFF/32, DD/32), 256, 0, stream>>>(W2, W2t,              FFF, DD, 0);
    concat_bias<<<3, 256, 0, stream>>>(bq, bk, bv, bqkv);

    ln_kernel<<<NROW, 256, 0, stream>>>(x, ln1w, ln1b, yb);

    // fused QKV GEMM with head-separating scatter epilogue (128-tile, BK=32)
    mfma_gemm<128,1><<<dim3(QKVN/128, NROW/128), 256, 0, stream>>>(
        yb, Wqkvt, bqkv, nullptr, nullptr, NROW, QKVN, DD, 0, 0, 1, qhb, khb, vtb);

    attn_mfma<<<dim3(BB*HH*(SS/128)), 256, 0, stream>>>(qhb, khb, vtb, aob);

    // projection + GELU + residual(x) -> out fp32   (64-row tiles, BK=64, 768 blocks)
    mfma_gemm<64,2><<<dim3(DD/128, NROW/64), 256, 0, stream>>>(
        aob, Wpt, bp, x, out, NROW, DD, DD, 1, 0, 0, nullptr, nullptr, nullptr);

    ln_kernel<<<NROW, 256, 0, stream>>>(out, ln2w, ln2b, yb);

    // FF1 + GELU -> hb bf16   (128-tile, BK=32)
    mfma_gemm<128,1><<<dim3(FFF/128, NROW/128), 256, 0, stream>>>(
        yb, W1t, b1, nullptr, hb, NROW, FFF, DD, 1, 1, 0, nullptr, nullptr, nullptr);

    // FF2 + GELU + residual(out) -> out fp32   (64-row tiles, BK=64, 768 blocks)
    mfma_gemm<64,2><<<dim3(DD/128, NROW/64), 256, 0, stream>>>(
        hb, W2t, b2, out, out, NROW, DD, FFF, 1, 0, 0, nullptr, nullptr, nullptr);
}

// Round 8
// 395.999 us; speedup vs baseline: 8.3454x; 1.0745x over previous
//
#include <hip/hip_runtime.h>
#include <hip/hip_bf16.h>
#include <math.h>

#define BB 8
#define SS 1024
#define DD 768
#define HH 12
#define HDD 64
#define FFF 3072
#define NROW (BB*SS)
#define QKVN (3*DD)

typedef __hip_bfloat16 bf16;
typedef __bf16 bf16x8 __attribute__((ext_vector_type(8)));
typedef float floatx4 __attribute__((ext_vector_type(4)));

// tanh-form GELU: ~9 VALU ops (exp+rcp) vs ~30 for erff; max abs err ~1e-3.
__device__ __forceinline__ float gelu_fast(float x) {
    float u = x * fmaf(0.07135481627f, x * x, 1.595769122f);
    float e = __expf(u);
    return x * e * __builtin_amdgcn_rcpf(e + 1.0f);
}

__device__ __forceinline__ unsigned short f2bfbits(float f) {
    bf16 h = __float2bfloat16(f);
    return __builtin_bit_cast(unsigned short, h);
}

__device__ __forceinline__ void gload16(const void* g, void* l) {
    __builtin_amdgcn_global_load_lds(
        (const __attribute__((address_space(1))) unsigned int*)g,
        (__attribute__((address_space(3))) unsigned int*)l, 16, 0, 0);
}

// ---------------- LayerNorm: fp32 in, bf16 out, one block per row ----------------
__global__ __launch_bounds__(256) void ln_kernel(const float* __restrict__ x,
                                                 const float* __restrict__ w,
                                                 const float* __restrict__ b,
                                                 bf16* __restrict__ y) {
    int row = blockIdx.x;
    const float* xr = x + (size_t)row * DD;
    bf16* yr = y + (size_t)row * DD;
    int tid = threadIdx.x;
    float v0 = xr[tid], v1 = xr[tid + 256], v2 = xr[tid + 512];
    __shared__ float red[256], red2[256];
    red[tid]  = v0 + v1 + v2;
    red2[tid] = v0*v0 + v1*v1 + v2*v2;
    __syncthreads();
    for (int off = 128; off > 0; off >>= 1) {
        if (tid < off) { red[tid] += red[tid+off]; red2[tid] += red2[tid+off]; }
        __syncthreads();
    }
    float mu  = red[0] * (1.0f / DD);
    float var = red2[0] * (1.0f / DD) - mu * mu;
    float inv = rsqrtf(var + 1e-5f);
    yr[tid]       = __float2bfloat16((v0 - mu) * inv * w[tid]       + b[tid]);
    yr[tid + 256] = __float2bfloat16((v1 - mu) * inv * w[tid + 256] + b[tid + 256]);
    yr[tid + 512] = __float2bfloat16((v2 - mu) * inv * w[tid + 512] + b[tid + 512]);
}

// ------------- fused weight prep: all transposes+casts + bias concat, ONE launch ---
// id<1728: Wq/Wk/Wv (headed) -> Wqkvt; <2304: Wp; <4608: W1; <6912: W2; else bias.
__global__ __launch_bounds__(256) void prep_kernel(
    const float* __restrict__ Wq, const float* __restrict__ Wk,
    const float* __restrict__ Wv, const float* __restrict__ Wp,
    const float* __restrict__ W1, const float* __restrict__ W2,
    const float* __restrict__ bq, const float* __restrict__ bk,
    const float* __restrict__ bv,
    bf16* __restrict__ Wqkvt, bf16* __restrict__ Wpt,
    bf16* __restrict__ W1t, bf16* __restrict__ W2t, float* __restrict__ bqkv)
{
    int id = blockIdx.x;
    if (id >= 6912) {
        int i = (id - 6912) * 256 + threadIdx.x;
        if (i < DD) { bqkv[i] = bq[i]; bqkv[DD + i] = bk[i]; bqkv[2*DD + i] = bv[i]; }
        return;
    }
    const float* src; bf16* dst; int K, N, hmode, local;
    if (id < 1728)      { K = DD;  N = DD;  hmode = 1; local = id % 576;
                          src = (id < 576) ? Wq : (id < 1152 ? Wk : Wv);
                          dst = Wqkvt + (size_t)(id / 576) * DD * DD; }
    else if (id < 2304) { K = DD;  N = DD;  hmode = 0; local = id - 1728; src = Wp; dst = Wpt; }
    else if (id < 4608) { K = DD;  N = FFF; hmode = 0; local = id - 2304; src = W1; dst = W1t; }
    else                { K = FFF; N = DD;  hmode = 0; local = id - 4608; src = W2; dst = W2t; }
    int ktiles = K / 32;
    int k0 = (local % ktiles) * 32, n0 = (local / ktiles) * 32;
    __shared__ float t[32][33];
    int tx = threadIdx.x & 31, ty4 = threadIdx.x >> 5;
    #pragma unroll
    for (int i = 0; i < 4; i++) {
        int k = k0 + ty4 * 4 + i;
        int n = n0 + tx;
        size_t si = hmode ? ((size_t)(n >> 6) * K * 64 + (size_t)k * 64 + (n & 63))
                          : ((size_t)k * N + n);
        t[ty4 * 4 + i][tx] = src[si];
    }
    __syncthreads();
    #pragma unroll
    for (int i = 0; i < 4; i++) {
        int n = n0 + ty4 * 4 + i;
        int k = k0 + tx;
        dst[(size_t)n * K + k] = __float2bfloat16(t[tx][ty4 * 4 + i]);
    }
}

// ---------------- MFMA bf16 GEMM, double-buffered: C = epi(A @ Bt^T) ---------------
// MT = rows/block; KH = 32-k sub-blocks per barrier (BK = 32*KH).
// LDS tiles chunk-XOR-swizzled (pos = chunk ^ ((row>>1)&3)): conflict-free frag reads.
template<int MT, int KH>
__global__ __launch_bounds__(256) void mfma_gemm(
    const bf16* __restrict__ A, const bf16* __restrict__ Bt,
    const float* __restrict__ bias, const float* __restrict__ resid,
    void* __restrict__ Cout, int M, int N, int K, int act, int out_bf16,
    int qkvmode, bf16* __restrict__ qhg, bf16* __restrict__ khg, bf16* __restrict__ vtg)
{
    constexpr int MFRAG = MT / 32;           // m-fragments per wave
    constexpr int ACH = MT * 4;              // A chunks per 32-k half
    __shared__ bf16 As[2][KH * MT * 32];
    __shared__ bf16 Bs[2][KH * 128 * 32];
    int tid = threadIdx.x;
    int row0 = blockIdx.y * MT, col0 = blockIdx.x * 128;
    int wave = tid >> 6, lane = tid & 63;
    int wm = (wave >> 1) * (MT / 2), wn = (wave & 1) * 64;
    int l16 = lane & 15, quad = lane >> 4;

    auto stage = [&](int k0, int buf) {
        #pragma unroll
        for (int i = 0; i < ACH * KH / 256; i++) {
            int c = tid + i * 256;
            int half = c / ACH, rem = c % ACH;
            int r = rem >> 2, pos = rem & 3;
            int ksw = k0 + half * 32 + ((pos ^ ((r >> 1) & 3)) << 3);
            gload16(A + (size_t)(row0 + r) * K + ksw, &As[buf][c * 8]);
        }
        #pragma unroll
        for (int i = 0; i < 2 * KH; i++) {
            int c = tid + i * 256;
            int half = c >> 9, rem = c & 511;
            int r = rem >> 2, pos = rem & 3;
            int ksw = k0 + half * 32 + ((pos ^ ((r >> 1) & 3)) << 3);
            gload16(Bt + (size_t)(col0 + r) * K + ksw, &Bs[buf][c * 8]);
        }
    };

    floatx4 acc[MFRAG][4] = {};

    stage(0, 0);
    int cur = 0;
    for (int k0 = 0; k0 < K; k0 += 32 * KH) {
        __syncthreads();                       // buf[cur] staged; all readers done w/ alt
        if (k0 + 32 * KH < K) stage(k0 + 32 * KH, cur ^ 1);
        #pragma unroll
        for (int s = 0; s < KH; s++) {
            bf16x8 af[MFRAG], bfr[4];
            #pragma unroll
            for (int mt = 0; mt < MFRAG; mt++) {
                int r = wm + mt * 16 + l16;
                int pos = quad ^ ((r >> 1) & 3);
                af[mt] = *(const bf16x8*)&As[cur][s * MT * 32 + r * 32 + pos * 8];
            }
            #pragma unroll
            for (int nt = 0; nt < 4; nt++) {
                int r = wn + nt * 16 + l16;
                int pos = quad ^ ((r >> 1) & 3);
                bfr[nt] = *(const bf16x8*)&Bs[cur][s * 4096 + r * 32 + pos * 8];
            }
            #pragma unroll
            for (int mt = 0; mt < MFRAG; mt++)
                #pragma unroll
                for (int nt = 0; nt < 4; nt++)
                    acc[mt][nt] = __builtin_amdgcn_mfma_f32_16x16x32_bf16(
                        af[mt], bfr[nt], acc[mt][nt], 0, 0, 0);
        }
        cur ^= 1;
    }

    if (qkvmode) {
        #pragma unroll
        for (int mt = 0; mt < MFRAG; mt++) {
            int rbase = row0 + wm + mt * 16 + quad * 4;
            int bq_ = rbase >> 10, sb = rbase & 1023;
            #pragma unroll
            for (int nt = 0; nt < 4; nt++) {
                int col = col0 + wn + nt * 16 + l16;
                float bcol = bias[col];
                if (col < DD) {
                    int hh = col >> 6, e = col & 63;
                    bf16* base = qhg + (((size_t)bq_ * HH + hh) * SS + sb) * 64 + e;
                    #pragma unroll
                    for (int r = 0; r < 4; r++)
                        base[(size_t)r * 64] = __float2bfloat16(acc[mt][nt][r] + bcol);
                } else if (col < 2 * DD) {
                    int cc = col - DD, hh = cc >> 6, e = cc & 63;
                    bf16* base = khg + (((size_t)bq_ * HH + hh) * SS) * 64;
                    #pragma unroll
                    for (int r = 0; r < 4; r++) {
                        int s = sb + r;
                        int pos = (((e >> 3) ^ (s & 7)) << 3) | (e & 7);
                        base[(size_t)s * 64 + pos] = __float2bfloat16(acc[mt][nt][r] + bcol);
                    }
                } else {
                    int cc = col - 2 * DD, hh = cc >> 6, e = cc & 63;
                    int c_t = sb >> 3;
                    int sc = (c_t & ~7) | ((c_t & 7) ^ (e & 7));
                    size_t off = (((size_t)bq_ * HH + hh) * 64 + e) * SS + sc * 8 + (sb & 7);
                    ushort4 pk;
                    pk.x = f2bfbits(acc[mt][nt][0] + bcol);
                    pk.y = f2bfbits(acc[mt][nt][1] + bcol);
                    pk.z = f2bfbits(acc[mt][nt][2] + bcol);
                    pk.w = f2bfbits(acc[mt][nt][3] + bcol);
                    *(ushort4*)&vtg[off] = pk;
                }
            }
        }
        return;
    }

    #pragma unroll
    for (int mt = 0; mt < MFRAG; mt++) {
        int rbase = row0 + wm + mt * 16 + quad * 4;
        #pragma unroll
        for (int nt = 0; nt < 4; nt++) {
            int col = col0 + wn + nt * 16 + l16;
            float bcol = bias[col];
            #pragma unroll
            for (int r = 0; r < 4; r++) {
                int row = rbase + r;
                float v = acc[mt][nt][r] + bcol;
                if (act) v = gelu_fast(v);
                if (resid) v += resid[(size_t)row * N + col];
                if (out_bf16) ((bf16*)Cout)[(size_t)row * N + col] = __float2bfloat16(v);
                else          ((float*)Cout)[(size_t)row * N + col] = v;
            }
        }
    }
}

// ---------------- MFMA flash attention: S^T form, no-max softmax -------------------
// Computes S^T = K·Q^T (A=K-frag, B=Q-frag) so P^T's C-layout gives each thread 4
// consecutive TOKENS -> one ds_write_b64 per fragment (vs 32 scalar b16). PV then
// computes O^T = V^T·P^T with the same MFMA count; O^T is transposed back through
// the wave-private LDS region for vectorized 16B global stores. l-reduction happens
// ONCE in the epilogue (2 shuffles). XCD-swizzled 1D grid for KV L2 locality.
__global__ __launch_bounds__(256) void attn_mfma(
    const bf16* __restrict__ qh, const bf16* __restrict__ kh,
    const bf16* __restrict__ vT, bf16* __restrict__ ao)
{
    __shared__ bf16 Ks[2][64 * 64];
    __shared__ bf16 Vs[2][64 * 64];
    __shared__ bf16 Ps[128 * 64];     // per-wave 32-row private regions

    int tid = threadIdx.x;
    int wave = tid >> 6, lane = tid & 63;
    int l16 = lane & 15, quad = lane >> 4;
    int id = blockIdx.x;
    int bh = (id & 7) * 12 + ((id >> 3) >> 3);
    int b = bh / HH, h = bh % HH;
    int s0 = ((id >> 3) & 7) * 128;
    int wm = wave * 32;

    const bf16* qbase = qh + ((size_t)bh * SS) * HDD;
    const bf16* kbase = kh + ((size_t)bh * SS) * HDD;
    const bf16* vbase = vT + ((size_t)bh * HDD) * SS;

    auto stage = [&](int t0, int buf) {
        #pragma unroll
        for (int i = 0; i < 2; i++) {
            int c = tid + i * 256;
            gload16(kbase + (size_t)t0 * 64 + c * 8, &Ks[buf][c * 8]);
            gload16(vbase + (size_t)(c >> 3) * SS + t0 + (c & 7) * 8, &Vs[buf][c * 8]);
        }
    };

    // Q fragments (same registers serve as B-fragments for S^T)
    bf16x8 qf[2][2];
    #pragma unroll
    for (int mt = 0; mt < 2; mt++)
        #pragma unroll
        for (int ks = 0; ks < 2; ks++)
            qf[mt][ks] = *(const bf16x8*)(qbase +
                (size_t)(s0 + wm + mt * 16 + l16) * HDD + ks * 32 + quad * 8);

    floatx4 oaccT[4][2] = {};    // [e-tile][m-tile], C-layout: col=m, row=e
    float lsum[2] = {};          // per m-tile partial (this thread's tokens)

    stage(0, 0);
    int cur = 0;
    for (int t0 = 0; t0 < SS; t0 += 64) {
        __syncthreads();
        if (t0 + 64 < SS) stage(t0 + 64, cur ^ 1);

        // ---- S^T = K Q^T (64 t x 32 m per wave) ----
        floatx4 st[4][2] = {};
        #pragma unroll
        for (int tt = 0; tt < 4; tt++) {
            int t = tt * 16 + l16;
            #pragma unroll
            for (int ks = 0; ks < 2; ks++) {
                int pos = (quad + 4 * ks) ^ (t & 7);
                bf16x8 kf = *(const bf16x8*)(&Ks[cur][t * 64 + pos * 8]);
                #pragma unroll
                for (int mt = 0; mt < 2; mt++)
                    st[tt][mt] = __builtin_amdgcn_mfma_f32_16x16x32_bf16(
                        kf, qf[mt][ks], st[tt][mt], 0, 0, 0);
            }
        }

        // ---- P^T = exp(S^T): 4 consecutive tokens per thread -> b64 LDS store ----
        #pragma unroll
        for (int tt = 0; tt < 4; tt++)
            #pragma unroll
            for (int mt = 0; mt < 2; mt++) {
                float p0 = __expf(st[tt][mt][0]);
                float p1 = __expf(st[tt][mt][1]);
                float p2 = __expf(st[tt][mt][2]);
                float p3 = __expf(st[tt][mt][3]);
                lsum[mt] += (p0 + p1) + (p2 + p3);
                int m = wm + mt * 16 + l16;
                int c = tt * 2 + (quad >> 1);          // token chunk
                ushort4 pk;
                pk.x = f2bfbits(p0); pk.y = f2bfbits(p1);
                pk.z = f2bfbits(p2); pk.w = f2bfbits(p3);
                *(ushort4*)&Ps[m * 64 + ((c ^ (m & 7)) << 3) + (quad & 1) * 4] = pk;
            }

        // ---- O^T += V^T P^T (64 e x 32 m per wave) ----
        #pragma unroll
        for (int ks = 0; ks < 2; ks++) {
            bf16x8 pf[2];
            #pragma unroll
            for (int mt = 0; mt < 2; mt++) {
                int m = wm + mt * 16 + l16;
                pf[mt] = *(const bf16x8*)(&Ps[m * 64 + (((quad + 4 * ks) ^ (m & 7)) << 3)]);
            }
            #pragma unroll
            for (int et = 0; et < 4; et++) {
                int e = et * 16 + l16;
                int vpos = (quad + 4 * ks) ^ (e & 7);
                bf16x8 vf = *(const bf16x8*)(&Vs[cur][e * 64 + vpos * 8]);
                #pragma unroll
                for (int mt = 0; mt < 2; mt++)
                    oaccT[et][mt] = __builtin_amdgcn_mfma_f32_16x16x32_bf16(
                        vf, pf[mt], oaccT[et][mt], 0, 0, 0);
            }
        }
        cur ^= 1;
    }

    // ---- epilogue: reduce l over quads (2 shuffles), scale, transpose via LDS ----
    float linv[2];
    #pragma unroll
    for (int mt = 0; mt < 2; mt++) {
        float l = lsum[mt];
        l += __shfl_xor(l, 16, 64);
        l += __shfl_xor(l, 32, 64);
        linv[mt] = __builtin_amdgcn_rcpf(l);
    }
    #pragma unroll
    for (int et = 0; et < 4; et++)
        #pragma unroll
        for (int mt = 0; mt < 2; mt++) {
            int m = wm + mt * 16 + l16;
            int c = et * 2 + (quad >> 1);              // e chunk
            ushort4 pk;
            pk.x = f2bfbits(oaccT[et][mt][0] * linv[mt]);
            pk.y = f2bfbits(oaccT[et][mt][1] * linv[mt]);
            pk.z = f2bfbits(oaccT[et][mt][2] * linv[mt]);
            pk.w = f2bfbits(oaccT[et][mt][3] * linv[mt]);
            *(ushort4*)&Ps[m * 64 + ((c ^ (m & 7)) << 3) + (quad & 1) * 4] = pk;
        }
    // wave-private region: in-wave LDS ordering suffices, no barrier needed
    int mrow = wm + (lane >> 1);
    bf16* op = ao + ((size_t)b * SS + s0 + mrow) * DD + h * HDD;
    #pragma unroll
    for (int i = 0; i < 4; i++) {
        int j = (lane & 1) * 4 + i;
        bf16x8 v = *(const bf16x8*)&Ps[mrow * 64 + ((j ^ (mrow & 7)) << 3)];
        *(bf16x8*)&op[j * 8] = v;
    }
}

// -----------------------------------------------------------------------------------
extern "C" void kernel_launch(void* const* d_in, const int* in_sizes, int n_in,
                              void* d_out, int out_size, void* d_ws, size_t ws_size,
                              hipStream_t stream)
{
    (void)in_sizes; (void)n_in; (void)out_size; (void)ws_size;
    const float* x    = (const float*)d_in[0];
    const float* ln1w = (const float*)d_in[1];
    const float* ln1b = (const float*)d_in[2];
    const float* Wq   = (const float*)d_in[3];
    const float* bq   = (const float*)d_in[4];
    const float* Wk   = (const float*)d_in[5];
    const float* bk   = (const float*)d_in[6];
    const float* Wv   = (const float*)d_in[7];
    const float* bv   = (const float*)d_in[8];
    const float* Wp   = (const float*)d_in[9];
    const float* bp   = (const float*)d_in[10];
    const float* ln2w = (const float*)d_in[11];
    const float* ln2b = (const float*)d_in[12];
    const float* W1   = (const float*)d_in[13];
    const float* b1   = (const float*)d_in[14];
    const float* W2   = (const float*)d_in[15];
    const float* b2   = (const float*)d_in[16];
    float* out = (float*)d_out;

    char* p = (char*)d_ws;
    auto alloc = [&](size_t bytes) { char* r = p; p += (bytes + 255) & ~255ull; return r; };
    bf16*  Wqkvt = (bf16*)alloc((size_t)QKVN * DD * 2);
    bf16*  Wpt   = (bf16*)alloc((size_t)DD * DD * 2);
    bf16*  W1t   = (bf16*)alloc((size_t)FFF * DD * 2);
    bf16*  W2t   = (bf16*)alloc((size_t)DD * FFF * 2);
    float* bqkv  = (float*)alloc((size_t)QKVN * 4);
    bf16*  yb    = (bf16*)alloc((size_t)NROW * DD * 2);
    char*  dynr  = alloc((size_t)NROW * DD * 2 + 3 * ((size_t)NROW * DD * 2));
    bf16*  aob   = (bf16*)dynr;                                // [row][768]
    bf16*  qhb   = (bf16*)(dynr + (size_t)NROW * DD * 2);      // [bh][s][64]
    bf16*  khb   = qhb + (size_t)NROW * DD;                    // swizzled
    bf16*  vtb   = khb + (size_t)NROW * DD;                    // [bh][e][1024] swizzled
    bf16*  hb    = (bf16*)dynr;   // FF intermediate (50MB) reuses aob+qkv region

    // fused weight prep: 6912 transpose tiles + 3 bias blocks, ONE launch
    prep_kernel<<<6915, 256, 0, stream>>>(Wq, Wk, Wv, Wp, W1, W2, bq, bk, bv,
                                          Wqkvt, Wpt, W1t, W2t, bqkv);

    ln_kernel<<<NROW, 256, 0, stream>>>(x, ln1w, ln1b, yb);

    // fused QKV GEMM with head-separating scatter epilogue (128-tile, BK=32)
    mfma_gemm<128,1><<<dim3(QKVN/128, NROW/128), 256, 0, stream>>>(
        yb, Wqkvt, bqkv, nullptr, nullptr, NROW, QKVN, DD, 0, 0, 1, qhb, khb, vtb);

    attn_mfma<<<dim3(BB*HH*(SS/128)), 256, 0, stream>>>(qhb, khb, vtb, aob);

    // projection + GELU + residual(x) -> out fp32   (64-row tiles, BK=64, 768 blocks)
    mfma_gemm<64,2><<<dim3(DD/128, NROW/64), 256, 0, stream>>>(
        aob, Wpt, bp, x, out, NROW, DD, DD, 1, 0, 0, nullptr, nullptr, nullptr);

    ln_kernel<<<NROW, 256, 0, stream>>>(out, ln2w, ln2b, yb);

    // FF1 + GELU -> hb bf16   (64-row tiles, BK=64: 3072 blocks, 12 blocks/CU)
    mfma_gemm<64,2><<<dim3(FFF/128, NROW/64), 256, 0, stream>>>(
        yb, W1t, b1, nullptr, hb, NROW, FFF, DD, 1, 1, 0, nullptr, nullptr, nullptr);

    // FF2 + GELU + residual(out) -> out fp32   (64-row tiles, BK=64, 768 blocks)
    mfma_gemm<64,2><<<dim3(DD/128, NROW/64), 256, 0, stream>>>(
        hb, W2t, b2, out, out, NROW, DD, FFF, 1, 0, 0, nullptr, nullptr, nullptr);
}

// Round 9
// 378.518 us; speedup vs baseline: 8.7308x; 1.0462x over previous
//
#include <hip/hip_runtime.h>
#include <hip/hip_bf16.h>
#include <math.h>

#define BB 8
#define SS 1024
#define DD 768
#define HH 12
#define HDD 64
#define FFF 3072
#define NROW (BB*SS)
#define QKVN (3*DD)

typedef __hip_bfloat16 bf16;
typedef __bf16 bf16x8 __attribute__((ext_vector_type(8)));
typedef float floatx4 __attribute__((ext_vector_type(4)));

// tanh-form GELU: ~9 VALU ops (exp+rcp) vs ~30 for erff; max abs err ~1e-3.
__device__ __forceinline__ float gelu_fast(float x) {
    float u = x * fmaf(0.07135481627f, x * x, 1.595769122f);
    float e = __expf(u);
    return x * e * __builtin_amdgcn_rcpf(e + 1.0f);
}

__device__ __forceinline__ unsigned short f2bfbits(float f) {
    bf16 h = __float2bfloat16(f);
    return __builtin_bit_cast(unsigned short, h);
}

__device__ __forceinline__ void gload16(const void* g, void* l) {
    __builtin_amdgcn_global_load_lds(
        (const __attribute__((address_space(1))) unsigned int*)g,
        (__attribute__((address_space(3))) unsigned int*)l, 16, 0, 0);
}

__device__ __forceinline__ float ld_as_float(const float* p)  { return *p; }
__device__ __forceinline__ float ld_as_float(const bf16* p)   { return __bfloat162float(*p); }

// ---------------- LayerNorm: T in, bf16 out, one block per row ---------------------
template<typename T>
__global__ __launch_bounds__(256) void ln_kernel(const T* __restrict__ x,
                                                 const float* __restrict__ w,
                                                 const float* __restrict__ b,
                                                 bf16* __restrict__ y) {
    int row = blockIdx.x;
    const T* xr = x + (size_t)row * DD;
    bf16* yr = y + (size_t)row * DD;
    int tid = threadIdx.x;
    float v0 = ld_as_float(xr + tid), v1 = ld_as_float(xr + tid + 256),
          v2 = ld_as_float(xr + tid + 512);
    __shared__ float red[256], red2[256];
    red[tid]  = v0 + v1 + v2;
    red2[tid] = v0*v0 + v1*v1 + v2*v2;
    __syncthreads();
    for (int off = 128; off > 0; off >>= 1) {
        if (tid < off) { red[tid] += red[tid+off]; red2[tid] += red2[tid+off]; }
        __syncthreads();
    }
    float mu  = red[0] * (1.0f / DD);
    float var = red2[0] * (1.0f / DD) - mu * mu;
    float inv = rsqrtf(var + 1e-5f);
    yr[tid]       = __float2bfloat16((v0 - mu) * inv * w[tid]       + b[tid]);
    yr[tid + 256] = __float2bfloat16((v1 - mu) * inv * w[tid + 256] + b[tid + 256]);
    yr[tid + 512] = __float2bfloat16((v2 - mu) * inv * w[tid + 512] + b[tid + 512]);
}

// ------------- fused weight prep: all transposes+casts + bias concat, ONE launch ---
__global__ __launch_bounds__(256) void prep_kernel(
    const float* __restrict__ Wq, const float* __restrict__ Wk,
    const float* __restrict__ Wv, const float* __restrict__ Wp,
    const float* __restrict__ W1, const float* __restrict__ W2,
    const float* __restrict__ bq, const float* __restrict__ bk,
    const float* __restrict__ bv,
    bf16* __restrict__ Wqkvt, bf16* __restrict__ Wpt,
    bf16* __restrict__ W1t, bf16* __restrict__ W2t, float* __restrict__ bqkv)
{
    int id = blockIdx.x;
    if (id >= 6912) {
        int i = (id - 6912) * 256 + threadIdx.x;
        if (i < DD) { bqkv[i] = bq[i]; bqkv[DD + i] = bk[i]; bqkv[2*DD + i] = bv[i]; }
        return;
    }
    const float* src; bf16* dst; int K, N, hmode, local;
    if (id < 1728)      { K = DD;  N = DD;  hmode = 1; local = id % 576;
                          src = (id < 576) ? Wq : (id < 1152 ? Wk : Wv);
                          dst = Wqkvt + (size_t)(id / 576) * DD * DD; }
    else if (id < 2304) { K = DD;  N = DD;  hmode = 0; local = id - 1728; src = Wp; dst = Wpt; }
    else if (id < 4608) { K = DD;  N = FFF; hmode = 0; local = id - 2304; src = W1; dst = W1t; }
    else                { K = FFF; N = DD;  hmode = 0; local = id - 4608; src = W2; dst = W2t; }
    int ktiles = K / 32;
    int k0 = (local % ktiles) * 32, n0 = (local / ktiles) * 32;
    __shared__ float t[32][33];
    int tx = threadIdx.x & 31, ty4 = threadIdx.x >> 5;
    #pragma unroll
    for (int i = 0; i < 4; i++) {
        int k = k0 + ty4 * 4 + i;
        int n = n0 + tx;
        size_t si = hmode ? ((size_t)(n >> 6) * K * 64 + (size_t)k * 64 + (n & 63))
                          : ((size_t)k * N + n);
        t[ty4 * 4 + i][tx] = src[si];
    }
    __syncthreads();
    #pragma unroll
    for (int i = 0; i < 4; i++) {
        int n = n0 + ty4 * 4 + i;
        int k = k0 + tx;
        dst[(size_t)n * K + k] = __float2bfloat16(t[tx][ty4 * 4 + i]);
    }
}

// ---------------- MFMA bf16 GEMM, double-buffered: C = epi(A @ Bt^T) ---------------
// 1D grid, XCD-cooperative: xcd = id&7 owns `py` full row-panels x all `nx` col
// tiles, so all blocks sharing an A-panel sit on ONE XCD's L2 (A fetched once per
// chip, sharers hit L2 not L3). LDS chunk-XOR-swizzled: conflict-free frag reads.
template<int MT, int KH>
__global__ __launch_bounds__(256) void mfma_gemm(
    const bf16* __restrict__ A, const bf16* __restrict__ Bt,
    const float* __restrict__ bias, const float* __restrict__ residf,
    const bf16* __restrict__ residb, void* __restrict__ Cout,
    int M, int N, int K, int act, int out_bf16, int nx, int py,
    int qkvmode, bf16* __restrict__ qhg, bf16* __restrict__ khg, bf16* __restrict__ vtg)
{
    constexpr int MFRAG = MT / 32;
    constexpr int ACH = MT * 4;
    __shared__ bf16 As[2][KH * MT * 32];
    __shared__ bf16 Bs[2][KH * 128 * 32];
    int tid = threadIdx.x;
    int id = blockIdx.x;
    int xcd = id & 7, slot = id >> 3;
    int row0 = (xcd * py + slot / nx) * MT, col0 = (slot % nx) * 128;
    int wave = tid >> 6, lane = tid & 63;
    int wm = (wave >> 1) * (MT / 2), wn = (wave & 1) * 64;
    int l16 = lane & 15, quad = lane >> 4;

    auto stage = [&](int k0, int buf) {
        #pragma unroll
        for (int i = 0; i < ACH * KH / 256; i++) {
            int c = tid + i * 256;
            int half = c / ACH, rem = c % ACH;
            int r = rem >> 2, pos = rem & 3;
            int ksw = k0 + half * 32 + ((pos ^ ((r >> 1) & 3)) << 3);
            gload16(A + (size_t)(row0 + r) * K + ksw, &As[buf][c * 8]);
        }
        #pragma unroll
        for (int i = 0; i < 2 * KH; i++) {
            int c = tid + i * 256;
            int half = c >> 9, rem = c & 511;
            int r = rem >> 2, pos = rem & 3;
            int ksw = k0 + half * 32 + ((pos ^ ((r >> 1) & 3)) << 3);
            gload16(Bt + (size_t)(col0 + r) * K + ksw, &Bs[buf][c * 8]);
        }
    };

    floatx4 acc[MFRAG][4] = {};

    stage(0, 0);
    int cur = 0;
    for (int k0 = 0; k0 < K; k0 += 32 * KH) {
        __syncthreads();
        if (k0 + 32 * KH < K) stage(k0 + 32 * KH, cur ^ 1);
        #pragma unroll
        for (int s = 0; s < KH; s++) {
            bf16x8 af[MFRAG], bfr[4];
            #pragma unroll
            for (int mt = 0; mt < MFRAG; mt++) {
                int r = wm + mt * 16 + l16;
                int pos = quad ^ ((r >> 1) & 3);
                af[mt] = *(const bf16x8*)&As[cur][s * MT * 32 + r * 32 + pos * 8];
            }
            #pragma unroll
            for (int nt = 0; nt < 4; nt++) {
                int r = wn + nt * 16 + l16;
                int pos = quad ^ ((r >> 1) & 3);
                bfr[nt] = *(const bf16x8*)&Bs[cur][s * 4096 + r * 32 + pos * 8];
            }
            #pragma unroll
            for (int mt = 0; mt < MFRAG; mt++)
                #pragma unroll
                for (int nt = 0; nt < 4; nt++)
                    acc[mt][nt] = __builtin_amdgcn_mfma_f32_16x16x32_bf16(
                        af[mt], bfr[nt], acc[mt][nt], 0, 0, 0);
        }
        cur ^= 1;
    }

    if (qkvmode) {
        #pragma unroll
        for (int mt = 0; mt < MFRAG; mt++) {
            int rbase = row0 + wm + mt * 16 + quad * 4;
            int bq_ = rbase >> 10, sb = rbase & 1023;
            #pragma unroll
            for (int nt = 0; nt < 4; nt++) {
                int col = col0 + wn + nt * 16 + l16;
                float bcol = bias[col];
                if (col < DD) {
                    int hh = col >> 6, e = col & 63;
                    bf16* base = qhg + (((size_t)bq_ * HH + hh) * SS + sb) * 64 + e;
                    #pragma unroll
                    for (int r = 0; r < 4; r++)
                        base[(size_t)r * 64] = __float2bfloat16(acc[mt][nt][r] + bcol);
                } else if (col < 2 * DD) {
                    int cc = col - DD, hh = cc >> 6, e = cc & 63;
                    bf16* base = khg + (((size_t)bq_ * HH + hh) * SS) * 64;
                    #pragma unroll
                    for (int r = 0; r < 4; r++) {
                        int s = sb + r;
                        int pos = (((e >> 3) ^ (s & 7)) << 3) | (e & 7);
                        base[(size_t)s * 64 + pos] = __float2bfloat16(acc[mt][nt][r] + bcol);
                    }
                } else {
                    int cc = col - 2 * DD, hh = cc >> 6, e = cc & 63;
                    int c_t = sb >> 3;
                    int sc = (c_t & ~7) | ((c_t & 7) ^ (e & 7));
                    size_t off = (((size_t)bq_ * HH + hh) * 64 + e) * SS + sc * 8 + (sb & 7);
                    ushort4 pk;
                    pk.x = f2bfbits(acc[mt][nt][0] + bcol);
                    pk.y = f2bfbits(acc[mt][nt][1] + bcol);
                    pk.z = f2bfbits(acc[mt][nt][2] + bcol);
                    pk.w = f2bfbits(acc[mt][nt][3] + bcol);
                    *(ushort4*)&vtg[off] = pk;
                }
            }
        }
        return;
    }

    #pragma unroll
    for (int mt = 0; mt < MFRAG; mt++) {
        int rbase = row0 + wm + mt * 16 + quad * 4;
        #pragma unroll
        for (int nt = 0; nt < 4; nt++) {
            int col = col0 + wn + nt * 16 + l16;
            float bcol = bias[col];
            #pragma unroll
            for (int r = 0; r < 4; r++) {
                int row = rbase + r;
                float v = acc[mt][nt][r] + bcol;
                if (act) v = gelu_fast(v);
                if (residf) v += residf[(size_t)row * N + col];
                if (residb) v += __bfloat162float(residb[(size_t)row * N + col]);
                if (out_bf16) ((bf16*)Cout)[(size_t)row * N + col] = __float2bfloat16(v);
                else          ((float*)Cout)[(size_t)row * N + col] = v;
            }
        }
    }
}

// ---------------- MFMA flash attention: S^T form, no-max softmax -------------------
__global__ __launch_bounds__(256) void attn_mfma(
    const bf16* __restrict__ qh, const bf16* __restrict__ kh,
    const bf16* __restrict__ vT, bf16* __restrict__ ao)
{
    __shared__ bf16 Ks[2][64 * 64];
    __shared__ bf16 Vs[2][64 * 64];
    __shared__ bf16 Ps[128 * 64];

    int tid = threadIdx.x;
    int wave = tid >> 6, lane = tid & 63;
    int l16 = lane & 15, quad = lane >> 4;
    int id = blockIdx.x;
    int bh = (id & 7) * 12 + ((id >> 3) >> 3);
    int b = bh / HH, h = bh % HH;
    int s0 = ((id >> 3) & 7) * 128;
    int wm = wave * 32;

    const bf16* qbase = qh + ((size_t)bh * SS) * HDD;
    const bf16* kbase = kh + ((size_t)bh * SS) * HDD;
    const bf16* vbase = vT + ((size_t)bh * HDD) * SS;

    auto stage = [&](int t0, int buf) {
        #pragma unroll
        for (int i = 0; i < 2; i++) {
            int c = tid + i * 256;
            gload16(kbase + (size_t)t0 * 64 + c * 8, &Ks[buf][c * 8]);
            gload16(vbase + (size_t)(c >> 3) * SS + t0 + (c & 7) * 8, &Vs[buf][c * 8]);
        }
    };

    bf16x8 qf[2][2];
    #pragma unroll
    for (int mt = 0; mt < 2; mt++)
        #pragma unroll
        for (int ks = 0; ks < 2; ks++)
            qf[mt][ks] = *(const bf16x8*)(qbase +
                (size_t)(s0 + wm + mt * 16 + l16) * HDD + ks * 32 + quad * 8);

    floatx4 oaccT[4][2] = {};
    float lsum[2] = {};

    stage(0, 0);
    int cur = 0;
    for (int t0 = 0; t0 < SS; t0 += 64) {
        __syncthreads();
        if (t0 + 64 < SS) stage(t0 + 64, cur ^ 1);

        floatx4 st[4][2] = {};
        #pragma unroll
        for (int tt = 0; tt < 4; tt++) {
            int t = tt * 16 + l16;
            #pragma unroll
            for (int ks = 0; ks < 2; ks++) {
                int pos = (quad + 4 * ks) ^ (t & 7);
                bf16x8 kf = *(const bf16x8*)(&Ks[cur][t * 64 + pos * 8]);
                #pragma unroll
                for (int mt = 0; mt < 2; mt++)
                    st[tt][mt] = __builtin_amdgcn_mfma_f32_16x16x32_bf16(
                        kf, qf[mt][ks], st[tt][mt], 0, 0, 0);
            }
        }

        #pragma unroll
        for (int tt = 0; tt < 4; tt++)
            #pragma unroll
            for (int mt = 0; mt < 2; mt++) {
                float p0 = __expf(st[tt][mt][0]);
                float p1 = __expf(st[tt][mt][1]);
                float p2 = __expf(st[tt][mt][2]);
                float p3 = __expf(st[tt][mt][3]);
                lsum[mt] += (p0 + p1) + (p2 + p3);
                int m = wm + mt * 16 + l16;
                int c = tt * 2 + (quad >> 1);
                ushort4 pk;
                pk.x = f2bfbits(p0); pk.y = f2bfbits(p1);
                pk.z = f2bfbits(p2); pk.w = f2bfbits(p3);
                *(ushort4*)&Ps[m * 64 + ((c ^ (m & 7)) << 3) + (quad & 1) * 4] = pk;
            }

        #pragma unroll
        for (int ks = 0; ks < 2; ks++) {
            bf16x8 pf[2];
            #pragma unroll
            for (int mt = 0; mt < 2; mt++) {
                int m = wm + mt * 16 + l16;
                pf[mt] = *(const bf16x8*)(&Ps[m * 64 + (((quad + 4 * ks) ^ (m & 7)) << 3)]);
            }
            #pragma unroll
            for (int et = 0; et < 4; et++) {
                int e = et * 16 + l16;
                int vpos = (quad + 4 * ks) ^ (e & 7);
                bf16x8 vf = *(const bf16x8*)(&Vs[cur][e * 64 + vpos * 8]);
                #pragma unroll
                for (int mt = 0; mt < 2; mt++)
                    oaccT[et][mt] = __builtin_amdgcn_mfma_f32_16x16x32_bf16(
                        vf, pf[mt], oaccT[et][mt], 0, 0, 0);
            }
        }
        cur ^= 1;
    }

    float linv[2];
    #pragma unroll
    for (int mt = 0; mt < 2; mt++) {
        float l = lsum[mt];
        l += __shfl_xor(l, 16, 64);
        l += __shfl_xor(l, 32, 64);
        linv[mt] = __builtin_amdgcn_rcpf(l);
    }
    #pragma unroll
    for (int et = 0; et < 4; et++)
        #pragma unroll
        for (int mt = 0; mt < 2; mt++) {
            int m = wm + mt * 16 + l16;
            int c = et * 2 + (quad >> 1);
            ushort4 pk;
            pk.x = f2bfbits(oaccT[et][mt][0] * linv[mt]);
            pk.y = f2bfbits(oaccT[et][mt][1] * linv[mt]);
            pk.z = f2bfbits(oaccT[et][mt][2] * linv[mt]);
            pk.w = f2bfbits(oaccT[et][mt][3] * linv[mt]);
            *(ushort4*)&Ps[m * 64 + ((c ^ (m & 7)) << 3) + (quad & 1) * 4] = pk;
        }
    int mrow = wm + (lane >> 1);
    bf16* op = ao + ((size_t)b * SS + s0 + mrow) * DD + h * HDD;
    #pragma unroll
    for (int i = 0; i < 4; i++) {
        int j = (lane & 1) * 4 + i;
        bf16x8 v = *(const bf16x8*)&Ps[mrow * 64 + ((j ^ (mrow & 7)) << 3)];
        *(bf16x8*)&op[j * 8] = v;
    }
}

// -----------------------------------------------------------------------------------
extern "C" void kernel_launch(void* const* d_in, const int* in_sizes, int n_in,
                              void* d_out, int out_size, void* d_ws, size_t ws_size,
                              hipStream_t stream)
{
    (void)in_sizes; (void)n_in; (void)out_size; (void)ws_size;
    const float* x    = (const float*)d_in[0];
    const float* ln1w = (const float*)d_in[1];
    const float* ln1b = (const float*)d_in[2];
    const float* Wq   = (const float*)d_in[3];
    const float* bq   = (const float*)d_in[4];
    const float* Wk   = (const float*)d_in[5];
    const float* bk   = (const float*)d_in[6];
    const float* Wv   = (const float*)d_in[7];
    const float* bv   = (const float*)d_in[8];
    const float* Wp   = (const float*)d_in[9];
    const float* bp   = (const float*)d_in[10];
    const float* ln2w = (const float*)d_in[11];
    const float* ln2b = (const float*)d_in[12];
    const float* W1   = (const float*)d_in[13];
    const float* b1   = (const float*)d_in[14];
    const float* W2   = (const float*)d_in[15];
    const float* b2   = (const float*)d_in[16];
    float* out = (float*)d_out;

    char* p = (char*)d_ws;
    auto alloc = [&](size_t bytes) { char* r = p; p += (bytes + 255) & ~255ull; return r; };
    bf16*  Wqkvt = (bf16*)alloc((size_t)QKVN * DD * 2);
    bf16*  Wpt   = (bf16*)alloc((size_t)DD * DD * 2);
    bf16*  W1t   = (bf16*)alloc((size_t)FFF * DD * 2);
    bf16*  W2t   = (bf16*)alloc((size_t)DD * FFF * 2);
    float* bqkv  = (float*)alloc((size_t)QKVN * 4);
    bf16*  yb    = (bf16*)alloc((size_t)NROW * DD * 2);
    bf16*  x1b   = (bf16*)alloc((size_t)NROW * DD * 2);        // residual stream 1, bf16
    char*  dynr  = alloc((size_t)NROW * DD * 2 + 3 * ((size_t)NROW * DD * 2));
    bf16*  aob   = (bf16*)dynr;                                // [row][768]
    bf16*  qhb   = (bf16*)(dynr + (size_t)NROW * DD * 2);      // [bh][s][64]
    bf16*  khb   = qhb + (size_t)NROW * DD;                    // swizzled
    bf16*  vtb   = khb + (size_t)NROW * DD;                    // [bh][e][1024] swizzled
    bf16*  hb    = (bf16*)dynr;   // FF intermediate (50MB) reuses aob+qkv region

    prep_kernel<<<6915, 256, 0, stream>>>(Wq, Wk, Wv, Wp, W1, W2, bq, bk, bv,
                                          Wqkvt, Wpt, W1t, W2t, bqkv);

    ln_kernel<float><<<NROW, 256, 0, stream>>>(x, ln1w, ln1b, yb);

    // fused QKV GEMM, head-separating scatter (MT=128: 64 panels, py=8, nx=18)
    mfma_gemm<128,1><<<1152, 256, 0, stream>>>(
        yb, Wqkvt, bqkv, nullptr, nullptr, nullptr, NROW, QKVN, DD, 0, 0, 18, 8,
        1, qhb, khb, vtb);

    attn_mfma<<<dim3(BB*HH*(SS/128)), 256, 0, stream>>>(qhb, khb, vtb, aob);

    // projection + GELU + residual(x fp32) -> x1 bf16  (128 panels, py=16, nx=6)
    mfma_gemm<64,2><<<768, 256, 0, stream>>>(
        aob, Wpt, bp, x, nullptr, x1b, NROW, DD, DD, 1, 1, 6, 16,
        0, nullptr, nullptr, nullptr);

    ln_kernel<bf16><<<NROW, 256, 0, stream>>>(x1b, ln2w, ln2b, yb);

    // FF1 + GELU -> hb bf16  (128 panels, py=16, nx=24)
    mfma_gemm<64,2><<<3072, 256, 0, stream>>>(
        yb, W1t, b1, nullptr, nullptr, hb, NROW, FFF, DD, 1, 1, 24, 16,
        0, nullptr, nullptr, nullptr);

    // FF2 + GELU + residual(x1 bf16) -> out fp32  (128 panels, py=16, nx=6)
    mfma_gemm<64,2><<<768, 256, 0, stream>>>(
        hb, W2t, b2, nullptr, x1b, out, NROW, DD, FFF, 1, 0, 6, 16,
        0, nullptr, nullptr, nullptr);
}